// Round 10
// baseline (245.597 us; speedup 1.0000x reference)
//
#include <hip/hip_runtime.h>

constexpr int B_ = 4;
constexpr int N_ = 2048;
constexpr int NFEAT_ = 256;
constexpr int NHEADS_ = 8;
constexpr float SLOPE_ = 0.1f;
constexpr float L2E = 1.4426950408889634f;   // log2(e)

typedef __attribute__((ext_vector_type(8))) __fp16 f16x8;
typedef __attribute__((ext_vector_type(2))) __fp16 f16x2;
typedef __attribute__((ext_vector_type(4))) float f32x4;

__device__ __forceinline__ f16x8 pack8(const float* v) {
  union { f16x2 h2[4]; f16x8 h8; } u;
  u.h2[0] = __builtin_amdgcn_cvt_pkrtz(v[0], v[1]);
  u.h2[1] = __builtin_amdgcn_cvt_pkrtz(v[2], v[3]);
  u.h2[2] = __builtin_amdgcn_cvt_pkrtz(v[4], v[5]);
  u.h2[3] = __builtin_amdgcn_cvt_pkrtz(v[6], v[7]);
  return u.h8;
}

// ---------------------------------------------------------------------------
// adj -> fragment-ordered mask: mask2[b][i16grp(128)][jt(32)][lane(64)] ushort
// ---------------------------------------------------------------------------
__global__ __launch_bounds__(256) void k_packmask(
    const int* __restrict__ adj, unsigned short* __restrict__ mask2)
{
  const int l = threadIdx.x & 63;
  const size_t gw = ((size_t)blockIdx.x * 256 + threadIdx.x) >> 6;
  const int jt = (int)(gw & 31);
  const int ig16 = (int)((gw >> 5) & 127);
  const int b = (int)(gw >> 12);
  const int q = l >> 4, c15 = l & 15;

  const int* base = adj + ((size_t)b * N_ + ig16 * 16) * N_ + jt * 64 + l;
  unsigned int msk = 0;
  #pragma unroll
  for (int r = 0; r < 16; ++r) {
    int a = base[(size_t)r * N_];
    unsigned long long bal = __ballot(a > 0);
    unsigned int v = (unsigned int)((bal >> (q * 8)) & 0xffull)
                   | ((unsigned int)((bal >> (q * 8 + 32)) & 0xffull) << 8);
    if (r == c15) msk = v;
  }
  mask2[gw * 64 + l] = (unsigned short)msk;
}

// ---------------------------------------------------------------------------
// row max over N_ (for s2max)
// ---------------------------------------------------------------------------
__global__ __launch_bounds__(256) void k_rowmax(
    const float* __restrict__ src, float* __restrict__ dst)
{
  int row = blockIdx.x, t = threadIdx.x;
  const float* p = src + (size_t)row * N_;
  float m = -INFINITY;
  #pragma unroll
  for (int k = 0; k < N_ / 256; ++k) m = fmaxf(m, p[t + k * 256]);
  #pragma unroll
  for (int off = 1; off < 64; off <<= 1) m = fmaxf(m, __shfl_xor(m, off, 64));
  __shared__ float sm[4];
  if ((t & 63) == 0) sm[t >> 6] = m;
  __syncthreads();
  if (t == 0) dst[row] = fmaxf(fmaxf(sm[0], sm[1]), fmaxf(sm[2], sm[3]));
}

// ---------------------------------------------------------------------------
// Wh f32 [8][256][64] -> WhB f16 MFMA-B-frag [h][ks 8][ft 4][lane 64][8]
// ---------------------------------------------------------------------------
__global__ __launch_bounds__(256) void k_prepwh(
    const float* __restrict__ Wh, __fp16* __restrict__ WhB)
{
  int l = threadIdx.x & 63;
  int s = (int)((blockIdx.x * 256 + threadIdx.x) >> 6);   // 0..255
  int h = s >> 5, ks = (s >> 2) & 7, ft = s & 3;
  const float* src = Wh + ((size_t)h * 256 + ks * 32 + (l >> 4) * 8) * 64 + ft * 16 + (l & 15);
  float v[8];
  #pragma unroll
  for (int j = 0; j < 8; ++j) v[j] = src[(size_t)j * 64];
  *(f16x8*)(WhB + (size_t)s * 512 + l * 8) = pack8(v);
}

// ---------------------------------------------------------------------------
// Wo f32 [512][128] -> WoB f16 B-frag [ks 16][ft 8][lane 64][8]
// ---------------------------------------------------------------------------
__global__ __launch_bounds__(256) void k_prepwo(
    const float* __restrict__ Wo, __fp16* __restrict__ WoB)
{
  int l = threadIdx.x & 63;
  int s = (int)((blockIdx.x * 256 + threadIdx.x) >> 6);   // 0..127
  int ks = s >> 3, ft = s & 7;
  const float* src = Wo + ((size_t)ks * 32 + (l >> 4) * 8) * 128 + ft * 16 + (l & 15);
  float v[8];
  #pragma unroll
  for (int j = 0; j < 8; ++j) v[j] = src[(size_t)j * 128];
  *(f16x8*)(WoB + (size_t)s * 512 + l * 8) = pack8(v);
}

// ---------------------------------------------------------------------------
// GEMM1 (MFMA): block = 16 n-rows x ALL 512 f (8 heads), 256 thr = 4 waves.
// ---------------------------------------------------------------------------
__global__ __launch_bounds__(256, 4) void k_gemm1(
    const float* __restrict__ x, const __fp16* __restrict__ WhB,
    const float* __restrict__ ah,
    __fp16* __restrict__ hB1, float* __restrict__ s1h, float* __restrict__ s2h)
{
  constexpr int XP = 264;
  __shared__ __fp16 xs[16 * XP];
  __shared__ __fp16 hT[512 * 16];

  const int t = threadIdx.x;
  const int bid = blockIdx.x;
  const int b = bid >> 7;
  const int n0 = (bid & 127) * 16;

  {  // stage x -> f16
    int r = t >> 4, k0 = (t & 15) * 16;
    const float* src = x + ((size_t)(b * N_) + n0 + r) * NFEAT_ + k0;
    float v0[8], v1[8];
    *(float4*)&v0[0] = *(const float4*)(src);
    *(float4*)&v0[4] = *(const float4*)(src + 4);
    *(float4*)&v1[0] = *(const float4*)(src + 8);
    *(float4*)&v1[4] = *(const float4*)(src + 12);
    *(f16x8*)&xs[r * XP + k0] = pack8(v0);
    *(f16x8*)&xs[r * XP + k0 + 8] = pack8(v1);
  }
  __syncthreads();

  const int w = t >> 6, l = t & 63;
  const int quad = l >> 4, c15 = l & 15;

  f32x4 acc[8];
  #pragma unroll
  for (int i = 0; i < 8; ++i) acc[i] = (f32x4){0.f, 0.f, 0.f, 0.f};

  for (int ks = 0; ks < 8; ++ks) {
    f16x8 af = *(const f16x8*)&xs[c15 * XP + ks * 32 + quad * 8];
    #pragma unroll
    for (int tt = 0; tt < 8; ++tt) {
      int hl = tt >> 2, ft = tt & 3;
      f16x8 bf = *(const f16x8*)(WhB +
          ((((size_t)(2 * w + hl) * 8 + ks) * 4 + ft) * 512) + l * 8);
      acc[tt] = __builtin_amdgcn_mfma_f32_16x16x32_f16(af, bf, acc[tt], 0, 0, 0);
    }
  }

  #pragma unroll
  for (int hl = 0; hl < 2; ++hl) {
    int head = 2 * w + hl;
    float a1v[4], a2v[4];
    #pragma unroll
    for (int ft = 0; ft < 4; ++ft) {
      a1v[ft] = ah[head * 128 + ft * 16 + c15] * L2E;
      a2v[ft] = ah[head * 128 + 64 + ft * 16 + c15] * L2E;
    }
    #pragma unroll
    for (int r = 0; r < 4; ++r) {
      float v1 = 0.f, v2 = 0.f;
      #pragma unroll
      for (int ft = 0; ft < 4; ++ft) {
        v1 = fmaf(acc[hl * 4 + ft][r], a1v[ft], v1);
        v2 = fmaf(acc[hl * 4 + ft][r], a2v[ft], v2);
      }
      #pragma unroll
      for (int off = 1; off < 16; off <<= 1) {
        v1 += __shfl_xor(v1, off, 64);
        v2 += __shfl_xor(v2, off, 64);
      }
      if (c15 == 0) {
        s1h[(size_t)(b * NHEADS_ + head) * N_ + n0 + quad * 4 + r] = v1;
        s2h[(size_t)(b * NHEADS_ + head) * N_ + n0 + quad * 4 + r] = v2;
      }
    }
  }

  #pragma unroll
  for (int tt = 0; tt < 8; ++tt) {
    int f = (2 * w + (tt >> 2)) * 64 + (tt & 3) * 16 + c15;
    #pragma unroll
    for (int r = 0; r < 4; ++r)
      hT[f * 16 + quad * 4 + r] = (__fp16)acc[tt][r];
  }
  __syncthreads();

  const int base_oct = (n0 >> 3) & 3;
  #pragma unroll
  for (int q = 0; q < 4; ++q) {
    int s = t + q * 256;
    int c15v = s & 15, oct = (s >> 4) & 1, ft = (s >> 5) & 3, head = s >> 7;
    f16x8 v = *(const f16x8*)&hT[(head * 64 + ft * 16 + c15v) * 16 + oct * 8];
    int lane0 = (base_oct + oct) * 16 + c15v;
    *(f16x8*)(hB1 +
        ((((size_t)(b * NHEADS_ + head) * 64 + (n0 >> 5)) * 4 + ft) * 512) + lane0 * 8) = v;
  }
}

// ---------------------------------------------------------------------------
// GEMM2 (MFMA): block = 16 n-rows x 128 f, 256 thr = 4 waves.
// ---------------------------------------------------------------------------
__global__ __launch_bounds__(256, 4) void k_gemm2(
    const __fp16* __restrict__ g1, const __fp16* __restrict__ WoB,
    const float* __restrict__ ao,
    __fp16* __restrict__ hB2, float* __restrict__ s1o, float* __restrict__ s2o)
{
  constexpr int GP = 520;
  __shared__ __fp16 gs[16 * GP];
  __shared__ __fp16 hT[128 * 16];
  __shared__ float sd1[4][16], sd2[4][16];

  const int t = threadIdx.x;
  const int bid = blockIdx.x;
  const int b = bid >> 7;
  const int n0 = (bid & 127) * 16;

  {
    int r = t >> 4, k0 = (t & 15) * 32;
    const __fp16* src = g1 + ((size_t)(b * N_) + n0 + r) * 512 + k0;
    #pragma unroll
    for (int i = 0; i < 4; ++i)
      *(f16x8*)&gs[r * GP + k0 + i * 8] = *(const f16x8*)(src + i * 8);
  }
  __syncthreads();

  const int w = t >> 6, l = t & 63;
  const int quad = l >> 4, c15 = l & 15;

  f32x4 acc[2];
  acc[0] = (f32x4){0.f, 0.f, 0.f, 0.f};
  acc[1] = (f32x4){0.f, 0.f, 0.f, 0.f};

  for (int ks = 0; ks < 16; ++ks) {
    f16x8 af = *(const f16x8*)&gs[c15 * GP + ks * 32 + quad * 8];
    #pragma unroll
    for (int tt = 0; tt < 2; ++tt) {
      int ft = 2 * w + tt;
      f16x8 bf = *(const f16x8*)(WoB + (((size_t)ks * 8 + ft) * 512) + l * 8);
      acc[tt] = __builtin_amdgcn_mfma_f32_16x16x32_f16(af, bf, acc[tt], 0, 0, 0);
    }
  }

  {
    float a1v[2], a2v[2];
    #pragma unroll
    for (int tt = 0; tt < 2; ++tt) {
      int f = (2 * w + tt) * 16 + c15;
      a1v[tt] = ao[f] * L2E;
      a2v[tt] = ao[128 + f] * L2E;
    }
    #pragma unroll
    for (int r = 0; r < 4; ++r) {
      float v1 = acc[0][r] * a1v[0] + acc[1][r] * a1v[1];
      float v2 = acc[0][r] * a2v[0] + acc[1][r] * a2v[1];
      #pragma unroll
      for (int off = 1; off < 16; off <<= 1) {
        v1 += __shfl_xor(v1, off, 64);
        v2 += __shfl_xor(v2, off, 64);
      }
      if (c15 == 0) { sd1[w][quad * 4 + r] = v1; sd2[w][quad * 4 + r] = v2; }
    }
  }

  #pragma unroll
  for (int tt = 0; tt < 2; ++tt) {
    int f = (2 * w + tt) * 16 + c15;
    #pragma unroll
    for (int r = 0; r < 4; ++r)
      hT[f * 16 + quad * 4 + r] = (__fp16)acc[tt][r];
  }
  __syncthreads();

  if (t < 16)
    s1o[(size_t)b * N_ + n0 + t] = sd1[0][t] + sd1[1][t] + sd1[2][t] + sd1[3][t];
  else if (t < 32) {
    int rr = t - 16;
    s2o[(size_t)b * N_ + n0 + rr] = sd2[0][rr] + sd2[1][rr] + sd2[2][rr] + sd2[3][rr];
  }

  {
    int c15v = t & 15, oct = (t >> 4) & 1, ft = t >> 5;
    f16x8 v = *(const f16x8*)&hT[(ft * 16 + c15v) * 16 + oct * 8];
    int base_oct = (n0 >> 3) & 3;
    int lane0 = (base_oct + oct) * 16 + c15v;
    *(f16x8*)(hB2 +
        (((size_t)(b * 64 + (n0 >> 5)) * 8 + ft) * 512) + lane0 * 8) = v;
  }
}

// ---------------------------------------------------------------------------
// MFMA flash attention with LDS-staged V tiles (barrier-pipelined dbuf):
// per block, each j-chunk's NRG waves cooperatively stage their V tile ONCE
// into LDS (regs->LDS, next tile's global loads issued before current tile's
// compute), all rowgroup waves consume via ds_read_b128. s2 row staged in
// LDS once. Mask rotated 1-ahead in registers. Cuts per-wave global V traffic
// by NRG and converts in-loop global latency to LDS latency.
// EPI0: 4 rowgroups x 2 jchunks, TJ=64. EPI1: 2 rg x 4 jq, TJ=32 (fs half).
// ---------------------------------------------------------------------------
template<int EPI>
__global__ __launch_bounds__(512) void k_att(
    const __fp16* __restrict__ hB, const float* __restrict__ s1,
    const float* __restrict__ s2, const float* __restrict__ s2max,
    const unsigned short* __restrict__ mask2,
    const float* __restrict__ bias, void* __restrict__ outp)
{
  constexpr int H    = (EPI == 0) ? 8 : 1;
  constexpr int NFT  = (EPI == 0) ? 4 : 8;
  constexpr int KSTR = NFT * 512;              // f16 per kstep
  constexpr int OSTR = (EPI == 0) ? 512 : 128;
  constexpr int NRG  = (EPI == 0) ? 4 : 2;
  constexpr int NJQ  = 8 / NRG;
  constexpr int JLEN = N_ / NJQ;
  constexpr int TJ   = (EPI == 0) ? 64 : 32;
  constexpr int NIT  = JLEN / TJ;
  constexpr int IBLK = NRG * 16;
  constexpr int NH   = TJ / 32;                // kstep-halves per tile
  constexpr int TILE = TJ * 64;                // f16 per tile (per fs view)
  constexpr int CPT  = (TILE * 2) / (NRG * 64 * 16);  // 16B loads per thread

  __shared__ __fp16 vbuf[NJQ][2][TILE];
  __shared__ float s2s[N_];

  const int tid = threadIdx.x;
  const int w = tid >> 6, l = tid & 63;
  const int quad = l >> 4, c15 = l & 15;
  const int rowg = w % NRG, jq = w / NRG;
  const int tc = rowg * 64 + l;                // thread index within chunk

  int idx = blockIdx.x;
  const int ig = idx % (N_ / IBLK); idx /= (N_ / IBLK);
  int head = 0, fs = 0;
  if constexpr (EPI == 0) { head = idx % 8; idx /= 8; }
  else                    { fs = idx % 2; idx /= 2; }
  const int b = idx;

  const int i0w = ig * IBLK + rowg * 16;
  const int colbase = (EPI == 0) ? head * 64 : fs * 64;

  const float* s1p = s1 + (size_t)(b * H + head) * N_;
  const float* s2p = s2 + (size_t)(b * H + head) * N_;
  const char* hBp = (const char*)(hB + (size_t)(b * H + head) * (N_ / 32) * KSTR
                                  + (EPI == 0 ? 0 : fs * 2048));
  const unsigned short* mp = mask2 + ((size_t)(b * 128 + (i0w >> 4)) * 32) * 64 + l;

  // stage s2 row into LDS (512 thr x float4 = 2048)
  *(float4*)&s2s[tid * 4] = *(const float4*)(s2p + tid * 4);

  const float s1v = s1p[i0w + c15];
  const float zm = s1v + s2max[b * H + head];
  const float m = fmaxf(zm, SLOPE_ * zm);      // exact unmasked row max
  const float p = s1v - m;
  const float cq = (SLOPE_ - 1.f) * m;

  f16x8 ones;
  #pragma unroll
  for (int i = 0; i < 8; ++i) ones[i] = (__fp16)1.0f;

  f32x4 acc[4], acc5;
  #pragma unroll
  for (int t = 0; t < 4; ++t) acc[t] = (f32x4){0.f, 0.f, 0.f, 0.f};
  acc5 = (f32x4){0.f, 0.f, 0.f, 0.f};

  const int jbase = jq * JLEN;

  uint4 stg[CPT];
  auto gload = [&](int j0) {
    const char* src = hBp + (size_t)(j0 >> 5) * (KSTR * 2);
    #pragma unroll
    for (int c = 0; c < CPT; ++c) {
      int off = (tc + c * NRG * 64) * 16;
      stg[c] = *(const uint4*)(src + (off >> 12) * (KSTR * 2) + (off & 4095));
    }
  };
  auto lwrite = [&](int slot) {
    char* d = (char*)&vbuf[jq][slot][0];
    #pragma unroll
    for (int c = 0; c < CPT; ++c) {
      int off = (tc + c * NRG * 64) * 16;
      *(uint4*)(d + off) = stg[c];
    }
  };

  gload(jbase);
  lwrite(0);
  unsigned int mk_cur = mp[(size_t)(jbase >> 6) * 64];
  __syncthreads();

  for (int it = 0; it < NIT; ++it) {
    const int cur = it & 1;
    const int j0 = jbase + it * TJ;
    unsigned int mk_next = 0;
    if (it + 1 < NIT) {
      gload(j0 + TJ);
      mk_next = mp[(size_t)((j0 + TJ) >> 6) * 64];
    }

    // scores from LDS s2
    float s2r[NH * 8];
    *(float4*)&s2r[0] = *(const float4*)&s2s[j0 + quad * 8];
    *(float4*)&s2r[4] = *(const float4*)&s2s[j0 + quad * 8 + 4];
    if constexpr (NH == 2) {
      *(float4*)&s2r[8]  = *(const float4*)&s2s[j0 + 32 + quad * 8];
      *(float4*)&s2r[12] = *(const float4*)&s2s[j0 + 32 + quad * 8 + 4];
    }

    f16x8 afr[NH];
    #pragma unroll
    for (int h = 0; h < NH; ++h) {
      unsigned int mbyte;
      if constexpr (EPI == 0) mbyte = (mk_cur >> (h * 8)) & 0xffu;
      else                    mbyte = (mk_cur >> (8 * ((j0 >> 5) & 1))) & 0xffu;
      float wgt[8];
      #pragma unroll
      for (int k = 0; k < 8; ++k) {
        float t0 = p + s2r[h * 8 + k];
        float t1 = fmaf(SLOPE_, t0, cq);
        float tm = fmaxf(t0, t1);
        float e = __builtin_amdgcn_exp2f(tm);
        int sel = (int)(mbyte << (31 - k)) >> 31;
        union { float f; int i; } u; u.f = e; u.i &= sel;
        wgt[k] = u.f;
      }
      afr[h] = pack8(wgt);
    }

    const __fp16* vb = &vbuf[jq][cur][0];
    #pragma unroll
    for (int h = 0; h < NH; ++h) {
      acc5 = __builtin_amdgcn_mfma_f32_16x16x32_f16(afr[h], ones, acc5, 0, 0, 0);
      #pragma unroll
      for (int t = 0; t < 4; ++t) {
        f16x8 bf = *(const f16x8*)(vb + h * 2048 + t * 512 + l * 8);
        acc[t] = __builtin_amdgcn_mfma_f32_16x16x32_f16(afr[h], bf, acc[t], 0, 0, 0);
      }
    }

    if (it + 1 < NIT) {
      lwrite(cur ^ 1);
      mk_cur = mk_next;
    }
    __syncthreads();
  }

  // ---- combine partials across j-chunks (overlay LDS; loop barrier done) ----
  auto pacc = (float(*)[NRG][16][64])(&vbuf[0][0][0]);
  auto pls  = (float(*)[NRG][16])(&s2s[0]);
  if (jq > 0) {
    #pragma unroll
    for (int t = 0; t < 4; ++t)
      #pragma unroll
      for (int r = 0; r < 4; ++r)
        pacc[jq - 1][rowg][quad * 4 + r][t * 16 + c15] = acc[t][r];
    if (c15 == 0) {
      #pragma unroll
      for (int r = 0; r < 4; ++r)
        pls[jq - 1][rowg][quad * 4 + r] = acc5[r];
    }
  }
  __syncthreads();
  if (jq == 0) {
    float Lrow[4];
    #pragma unroll
    for (int r = 0; r < 4; ++r) Lrow[r] = acc5[r];
    #pragma unroll
    for (int q = 0; q < NJQ - 1; ++q) {
      #pragma unroll
      for (int t = 0; t < 4; ++t)
        #pragma unroll
        for (int r = 0; r < 4; ++r)
          acc[t][r] += pacc[q][rowg][quad * 4 + r][t * 16 + c15];
      #pragma unroll
      for (int r = 0; r < 4; ++r) Lrow[r] += pls[q][rowg][quad * 4 + r];
    }
    float lr[4];
    #pragma unroll
    for (int r = 0; r < 4; ++r) lr[r] = 1.f / Lrow[r];

    #pragma unroll
    for (int t = 0; t < 4; ++t) {
      const float bv = bias[colbase + t * 16 + c15];
      #pragma unroll
      for (int r = 0; r < 4; ++r) {
        const int i = i0w + quad * 4 + r;
        float v = acc[t][r] * lr[r] + bv;
        if constexpr (EPI == 0) {
          v = (v > 0.f) ? v : expm1f(v);      // elu
          ((__fp16*)outp)[(size_t)(b * N_ + i) * OSTR + colbase + t * 16 + c15] = (__fp16)v;
        } else {
          v = fmaxf(v, 0.f);                  // relu(elu)=relu
          ((float*)outp)[(size_t)(b * N_ + i) * OSTR + colbase + t * 16 + c15] = v;
        }
      }
    }
  }
}

// ---------------------------------------------------------------------------
extern "C" void kernel_launch(void* const* d_in, const int* in_sizes, int n_in,
                              void* d_out, int out_size, void* d_ws, size_t ws_size,
                              hipStream_t stream) {
  const float* x   = (const float*)d_in[0];
  const int*   adj = (const int*)d_in[1];
  const float* Wh  = (const float*)d_in[2];
  const float* ah  = (const float*)d_in[3];
  const float* bh  = (const float*)d_in[4];
  const float* Wo  = (const float*)d_in[5];
  const float* ao  = (const float*)d_in[6];
  const float* bo  = (const float*)d_in[7];
  float* out = (float*)d_out;

  float* ws   = (float*)d_ws;
  float* s1h  = ws;                                   // B*8*N
  float* s2h  = s1h  + (size_t)B_ * NHEADS_ * N_;
  float* s1o  = s2h  + (size_t)B_ * NHEADS_ * N_;     // B*N
  float* s2o  = s1o  + (size_t)B_ * N_;
  float* s2mh = s2o  + (size_t)B_ * N_;               // 32 (pad 64)
  float* s2mo = s2mh + 64;                            // 4 (pad 64)
  __fp16* g1  = (__fp16*)(s2mo + 64);                 // B*N*512 f16 (8 MB)
  __fp16* hB1 = g1  + (size_t)B_ * N_ * 512;          // 8 MB
  __fp16* hB2 = hB1 + (size_t)B_ * NHEADS_ * N_ * 64; // 2 MB
  __fp16* WhB = hB2 + (size_t)B_ * N_ * 128;          // 256 KB
  __fp16* WoB = WhB + (size_t)8 * 256 * 64;           // 128 KB
  unsigned short* mask2 = (unsigned short*)(WoB + (size_t)512 * 128); // 2 MB

  k_packmask<<<(B_ * 128 * 32 * 64) / 256, 256, 0, stream>>>(adj, mask2);
  k_prepwh<<<64, 256, 0, stream>>>(Wh, WhB);
  k_prepwo<<<32, 256, 0, stream>>>(Wo, WoB);
  k_gemm1<<<B_ * (N_ / 16), 256, 0, stream>>>(x, WhB, ah, hB1, s1h, s2h);
  k_rowmax<<<B_ * NHEADS_, 256, 0, stream>>>(s2h, s2mh);
  k_att<0><<<B_ * NHEADS_ * (N_ / 64), 512, 0, stream>>>(
      hB1, s1h, s2h, s2mh, mask2, bh, (void*)g1);
  k_gemm2<<<B_ * (N_ / 16), 256, 0, stream>>>(g1, WoB, ao, hB2, s1o, s2o);
  k_rowmax<<<B_, 256, 0, stream>>>(s2o, s2mo);
  k_att<1><<<B_ * 2 * (N_ / 32), 512, 0, stream>>>(
      hB2, s1o, s2o, s2mo, mask2, bo, (void*)out);
}

// Round 11
// 242.784 us; speedup vs baseline: 1.0116x; 1.0116x over previous
//
#include <hip/hip_runtime.h>

constexpr int B_ = 4;
constexpr int N_ = 2048;
constexpr int NFEAT_ = 256;
constexpr int NHEADS_ = 8;
constexpr float SLOPE_ = 0.1f;
constexpr float L2E = 1.4426950408889634f;   // log2(e)

typedef __attribute__((ext_vector_type(8))) __fp16 f16x8;
typedef __attribute__((ext_vector_type(2))) __fp16 f16x2;
typedef __attribute__((ext_vector_type(4))) float f32x4;

__device__ __forceinline__ f16x8 pack8(const float* v) {
  union { f16x2 h2[4]; f16x8 h8; } u;
  u.h2[0] = __builtin_amdgcn_cvt_pkrtz(v[0], v[1]);
  u.h2[1] = __builtin_amdgcn_cvt_pkrtz(v[2], v[3]);
  u.h2[2] = __builtin_amdgcn_cvt_pkrtz(v[4], v[5]);
  u.h2[3] = __builtin_amdgcn_cvt_pkrtz(v[6], v[7]);
  return u.h8;
}

// ---------------------------------------------------------------------------
// adj -> fragment-ordered mask: mask2[b][i16grp(128)][jt(32)][lane(64)] ushort
// ---------------------------------------------------------------------------
__global__ __launch_bounds__(256) void k_packmask(
    const int* __restrict__ adj, unsigned short* __restrict__ mask2)
{
  const int l = threadIdx.x & 63;
  const size_t gw = ((size_t)blockIdx.x * 256 + threadIdx.x) >> 6;
  const int jt = (int)(gw & 31);
  const int ig16 = (int)((gw >> 5) & 127);
  const int b = (int)(gw >> 12);
  const int q = l >> 4, c15 = l & 15;

  const int* base = adj + ((size_t)b * N_ + ig16 * 16) * N_ + jt * 64 + l;
  unsigned int msk = 0;
  #pragma unroll
  for (int r = 0; r < 16; ++r) {
    int a = base[(size_t)r * N_];
    unsigned long long bal = __ballot(a > 0);
    unsigned int v = (unsigned int)((bal >> (q * 8)) & 0xffull)
                   | ((unsigned int)((bal >> (q * 8 + 32)) & 0xffull) << 8);
    if (r == c15) msk = v;
  }
  mask2[gw * 64 + l] = (unsigned short)msk;
}

// ---------------------------------------------------------------------------
// row max over N_ (for s2max)
// ---------------------------------------------------------------------------
__global__ __launch_bounds__(256) void k_rowmax(
    const float* __restrict__ src, float* __restrict__ dst)
{
  int row = blockIdx.x, t = threadIdx.x;
  const float* p = src + (size_t)row * N_;
  float m = -INFINITY;
  #pragma unroll
  for (int k = 0; k < N_ / 256; ++k) m = fmaxf(m, p[t + k * 256]);
  #pragma unroll
  for (int off = 1; off < 64; off <<= 1) m = fmaxf(m, __shfl_xor(m, off, 64));
  __shared__ float sm[4];
  if ((t & 63) == 0) sm[t >> 6] = m;
  __syncthreads();
  if (t == 0) dst[row] = fmaxf(fmaxf(sm[0], sm[1]), fmaxf(sm[2], sm[3]));
}

// ---------------------------------------------------------------------------
// Wh f32 [8][256][64] -> WhB f16 MFMA-B-frag [h][ks 8][ft 4][lane 64][8]
// ---------------------------------------------------------------------------
__global__ __launch_bounds__(256) void k_prepwh(
    const float* __restrict__ Wh, __fp16* __restrict__ WhB)
{
  int l = threadIdx.x & 63;
  int s = (int)((blockIdx.x * 256 + threadIdx.x) >> 6);   // 0..255
  int h = s >> 5, ks = (s >> 2) & 7, ft = s & 3;
  const float* src = Wh + ((size_t)h * 256 + ks * 32 + (l >> 4) * 8) * 64 + ft * 16 + (l & 15);
  float v[8];
  #pragma unroll
  for (int j = 0; j < 8; ++j) v[j] = src[(size_t)j * 64];
  *(f16x8*)(WhB + (size_t)s * 512 + l * 8) = pack8(v);
}

// ---------------------------------------------------------------------------
// Wo f32 [512][128] -> WoB f16 B-frag [ks 16][ft 8][lane 64][8]
// ---------------------------------------------------------------------------
__global__ __launch_bounds__(256) void k_prepwo(
    const float* __restrict__ Wo, __fp16* __restrict__ WoB)
{
  int l = threadIdx.x & 63;
  int s = (int)((blockIdx.x * 256 + threadIdx.x) >> 6);   // 0..127
  int ks = s >> 3, ft = s & 7;
  const float* src = Wo + ((size_t)ks * 32 + (l >> 4) * 8) * 128 + ft * 16 + (l & 15);
  float v[8];
  #pragma unroll
  for (int j = 0; j < 8; ++j) v[j] = src[(size_t)j * 128];
  *(f16x8*)(WoB + (size_t)s * 512 + l * 8) = pack8(v);
}

// ---------------------------------------------------------------------------
// GEMM1 (MFMA): block = 16 n-rows x ALL 512 f (8 heads), 256 thr = 4 waves.
// ---------------------------------------------------------------------------
__global__ __launch_bounds__(256, 4) void k_gemm1(
    const float* __restrict__ x, const __fp16* __restrict__ WhB,
    const float* __restrict__ ah,
    __fp16* __restrict__ hB1, float* __restrict__ s1h, float* __restrict__ s2h)
{
  constexpr int XP = 264;
  __shared__ __fp16 xs[16 * XP];
  __shared__ __fp16 hT[512 * 16];

  const int t = threadIdx.x;
  const int bid = blockIdx.x;
  const int b = bid >> 7;
  const int n0 = (bid & 127) * 16;

  {  // stage x -> f16
    int r = t >> 4, k0 = (t & 15) * 16;
    const float* src = x + ((size_t)(b * N_) + n0 + r) * NFEAT_ + k0;
    float v0[8], v1[8];
    *(float4*)&v0[0] = *(const float4*)(src);
    *(float4*)&v0[4] = *(const float4*)(src + 4);
    *(float4*)&v1[0] = *(const float4*)(src + 8);
    *(float4*)&v1[4] = *(const float4*)(src + 12);
    *(f16x8*)&xs[r * XP + k0] = pack8(v0);
    *(f16x8*)&xs[r * XP + k0 + 8] = pack8(v1);
  }
  __syncthreads();

  const int w = t >> 6, l = t & 63;
  const int quad = l >> 4, c15 = l & 15;

  f32x4 acc[8];
  #pragma unroll
  for (int i = 0; i < 8; ++i) acc[i] = (f32x4){0.f, 0.f, 0.f, 0.f};

  for (int ks = 0; ks < 8; ++ks) {
    f16x8 af = *(const f16x8*)&xs[c15 * XP + ks * 32 + quad * 8];
    #pragma unroll
    for (int tt = 0; tt < 8; ++tt) {
      int hl = tt >> 2, ft = tt & 3;
      f16x8 bf = *(const f16x8*)(WhB +
          ((((size_t)(2 * w + hl) * 8 + ks) * 4 + ft) * 512) + l * 8);
      acc[tt] = __builtin_amdgcn_mfma_f32_16x16x32_f16(af, bf, acc[tt], 0, 0, 0);
    }
  }

  #pragma unroll
  for (int hl = 0; hl < 2; ++hl) {
    int head = 2 * w + hl;
    float a1v[4], a2v[4];
    #pragma unroll
    for (int ft = 0; ft < 4; ++ft) {
      a1v[ft] = ah[head * 128 + ft * 16 + c15] * L2E;
      a2v[ft] = ah[head * 128 + 64 + ft * 16 + c15] * L2E;
    }
    #pragma unroll
    for (int r = 0; r < 4; ++r) {
      float v1 = 0.f, v2 = 0.f;
      #pragma unroll
      for (int ft = 0; ft < 4; ++ft) {
        v1 = fmaf(acc[hl * 4 + ft][r], a1v[ft], v1);
        v2 = fmaf(acc[hl * 4 + ft][r], a2v[ft], v2);
      }
      #pragma unroll
      for (int off = 1; off < 16; off <<= 1) {
        v1 += __shfl_xor(v1, off, 64);
        v2 += __shfl_xor(v2, off, 64);
      }
      if (c15 == 0) {
        s1h[(size_t)(b * NHEADS_ + head) * N_ + n0 + quad * 4 + r] = v1;
        s2h[(size_t)(b * NHEADS_ + head) * N_ + n0 + quad * 4 + r] = v2;
      }
    }
  }

  #pragma unroll
  for (int tt = 0; tt < 8; ++tt) {
    int f = (2 * w + (tt >> 2)) * 64 + (tt & 3) * 16 + c15;
    #pragma unroll
    for (int r = 0; r < 4; ++r)
      hT[f * 16 + quad * 4 + r] = (__fp16)acc[tt][r];
  }
  __syncthreads();

  const int base_oct = (n0 >> 3) & 3;
  #pragma unroll
  for (int q = 0; q < 4; ++q) {
    int s = t + q * 256;
    int c15v = s & 15, oct = (s >> 4) & 1, ft = (s >> 5) & 3, head = s >> 7;
    f16x8 v = *(const f16x8*)&hT[(head * 64 + ft * 16 + c15v) * 16 + oct * 8];
    int lane0 = (base_oct + oct) * 16 + c15v;
    *(f16x8*)(hB1 +
        ((((size_t)(b * NHEADS_ + head) * 64 + (n0 >> 5)) * 4 + ft) * 512) + lane0 * 8) = v;
  }
}

// ---------------------------------------------------------------------------
// GEMM2 (MFMA): block = 16 n-rows x 128 f, 256 thr = 4 waves.
// ---------------------------------------------------------------------------
__global__ __launch_bounds__(256, 4) void k_gemm2(
    const __fp16* __restrict__ g1, const __fp16* __restrict__ WoB,
    const float* __restrict__ ao,
    __fp16* __restrict__ hB2, float* __restrict__ s1o, float* __restrict__ s2o)
{
  constexpr int GP = 520;
  __shared__ __fp16 gs[16 * GP];
  __shared__ __fp16 hT[128 * 16];
  __shared__ float sd1[4][16], sd2[4][16];

  const int t = threadIdx.x;
  const int bid = blockIdx.x;
  const int b = bid >> 7;
  const int n0 = (bid & 127) * 16;

  {
    int r = t >> 4, k0 = (t & 15) * 32;
    const __fp16* src = g1 + ((size_t)(b * N_) + n0 + r) * 512 + k0;
    #pragma unroll
    for (int i = 0; i < 4; ++i)
      *(f16x8*)&gs[r * GP + k0 + i * 8] = *(const f16x8*)(src + i * 8);
  }
  __syncthreads();

  const int w = t >> 6, l = t & 63;
  const int quad = l >> 4, c15 = l & 15;

  f32x4 acc[2];
  acc[0] = (f32x4){0.f, 0.f, 0.f, 0.f};
  acc[1] = (f32x4){0.f, 0.f, 0.f, 0.f};

  for (int ks = 0; ks < 16; ++ks) {
    f16x8 af = *(const f16x8*)&gs[c15 * GP + ks * 32 + quad * 8];
    #pragma unroll
    for (int tt = 0; tt < 2; ++tt) {
      int ft = 2 * w + tt;
      f16x8 bf = *(const f16x8*)(WoB + (((size_t)ks * 8 + ft) * 512) + l * 8);
      acc[tt] = __builtin_amdgcn_mfma_f32_16x16x32_f16(af, bf, acc[tt], 0, 0, 0);
    }
  }

  {
    float a1v[2], a2v[2];
    #pragma unroll
    for (int tt = 0; tt < 2; ++tt) {
      int f = (2 * w + tt) * 16 + c15;
      a1v[tt] = ao[f] * L2E;
      a2v[tt] = ao[128 + f] * L2E;
    }
    #pragma unroll
    for (int r = 0; r < 4; ++r) {
      float v1 = acc[0][r] * a1v[0] + acc[1][r] * a1v[1];
      float v2 = acc[0][r] * a2v[0] + acc[1][r] * a2v[1];
      #pragma unroll
      for (int off = 1; off < 16; off <<= 1) {
        v1 += __shfl_xor(v1, off, 64);
        v2 += __shfl_xor(v2, off, 64);
      }
      if (c15 == 0) { sd1[w][quad * 4 + r] = v1; sd2[w][quad * 4 + r] = v2; }
    }
  }

  #pragma unroll
  for (int tt = 0; tt < 2; ++tt) {
    int f = (2 * w + tt) * 16 + c15;
    #pragma unroll
    for (int r = 0; r < 4; ++r)
      hT[f * 16 + quad * 4 + r] = (__fp16)acc[tt][r];
  }
  __syncthreads();

  if (t < 16)
    s1o[(size_t)b * N_ + n0 + t] = sd1[0][t] + sd1[1][t] + sd1[2][t] + sd1[3][t];
  else if (t < 32) {
    int rr = t - 16;
    s2o[(size_t)b * N_ + n0 + rr] = sd2[0][rr] + sd2[1][rr] + sd2[2][rr] + sd2[3][rr];
  }

  {
    int c15v = t & 15, oct = (t >> 4) & 1, ft = t >> 5;
    f16x8 v = *(const f16x8*)&hT[(ft * 16 + c15v) * 16 + oct * 8];
    int base_oct = (n0 >> 3) & 3;
    int lane0 = (base_oct + oct) * 16 + c15v;
    *(f16x8*)(hB2 +
        (((size_t)(b * 64 + (n0 >> 5)) * 8 + ft) * 512) + lane0 * 8) = v;
  }
}

// ---------------------------------------------------------------------------
// MFMA flash attention with LDS-staged V tiles (barrier-pipelined dbuf).
// __launch_bounds__(512, 4): 128-VGPR cap — R10's missing 2nd arg made the
// compiler target 8 waves/SIMD (32 VGPR) and SPILL the stg[] prefetch
// buffers to scratch (WRITE_SIZE 8->167 MB). 2 blocks/CU (LDS 40KB) is the
// balanced point.
// ---------------------------------------------------------------------------
template<int EPI>
__global__ __launch_bounds__(512, 4) void k_att(
    const __fp16* __restrict__ hB, const float* __restrict__ s1,
    const float* __restrict__ s2, const float* __restrict__ s2max,
    const unsigned short* __restrict__ mask2,
    const float* __restrict__ bias, void* __restrict__ outp)
{
  constexpr int H    = (EPI == 0) ? 8 : 1;
  constexpr int NFT  = (EPI == 0) ? 4 : 8;
  constexpr int KSTR = NFT * 512;              // f16 per kstep
  constexpr int OSTR = (EPI == 0) ? 512 : 128;
  constexpr int NRG  = (EPI == 0) ? 4 : 2;
  constexpr int NJQ  = 8 / NRG;
  constexpr int JLEN = N_ / NJQ;
  constexpr int TJ   = (EPI == 0) ? 64 : 32;
  constexpr int NIT  = JLEN / TJ;
  constexpr int IBLK = NRG * 16;
  constexpr int NH   = TJ / 32;                // kstep-halves per tile
  constexpr int TILE = TJ * 64;                // f16 per tile (per fs view)
  constexpr int CPT  = (TILE * 2) / (NRG * 64 * 16);  // 16B loads per thread

  __shared__ __fp16 vbuf[NJQ][2][TILE];
  __shared__ float s2s[N_];

  const int tid = threadIdx.x;
  const int w = tid >> 6, l = tid & 63;
  const int quad = l >> 4, c15 = l & 15;
  const int rowg = w % NRG, jq = w / NRG;
  const int tc = rowg * 64 + l;                // thread index within chunk

  int idx = blockIdx.x;
  const int ig = idx % (N_ / IBLK); idx /= (N_ / IBLK);
  int head = 0, fs = 0;
  if constexpr (EPI == 0) { head = idx % 8; idx /= 8; }
  else                    { fs = idx % 2; idx /= 2; }
  const int b = idx;

  const int i0w = ig * IBLK + rowg * 16;
  const int colbase = (EPI == 0) ? head * 64 : fs * 64;

  const float* s1p = s1 + (size_t)(b * H + head) * N_;
  const float* s2p = s2 + (size_t)(b * H + head) * N_;
  const char* hBp = (const char*)(hB + (size_t)(b * H + head) * (N_ / 32) * KSTR
                                  + (EPI == 0 ? 0 : fs * 2048));
  const unsigned short* mp = mask2 + ((size_t)(b * 128 + (i0w >> 4)) * 32) * 64 + l;

  // stage s2 row into LDS (512 thr x float4 = 2048)
  *(float4*)&s2s[tid * 4] = *(const float4*)(s2p + tid * 4);

  const float s1v = s1p[i0w + c15];
  const float zm = s1v + s2max[b * H + head];
  const float m = fmaxf(zm, SLOPE_ * zm);      // exact unmasked row max
  const float p = s1v - m;
  const float cq = (SLOPE_ - 1.f) * m;

  f16x8 ones;
  #pragma unroll
  for (int i = 0; i < 8; ++i) ones[i] = (__fp16)1.0f;

  f32x4 acc[4], acc5;
  #pragma unroll
  for (int t = 0; t < 4; ++t) acc[t] = (f32x4){0.f, 0.f, 0.f, 0.f};
  acc5 = (f32x4){0.f, 0.f, 0.f, 0.f};

  const int jbase = jq * JLEN;

  uint4 stg[CPT];
  auto gload = [&](int j0) {
    const char* src = hBp + (size_t)(j0 >> 5) * (KSTR * 2);
    #pragma unroll
    for (int c = 0; c < CPT; ++c) {
      int off = (tc + c * NRG * 64) * 16;
      stg[c] = *(const uint4*)(src + (off >> 12) * (KSTR * 2) + (off & 4095));
    }
  };
  auto lwrite = [&](int slot) {
    char* d = (char*)&vbuf[jq][slot][0];
    #pragma unroll
    for (int c = 0; c < CPT; ++c) {
      int off = (tc + c * NRG * 64) * 16;
      *(uint4*)(d + off) = stg[c];
    }
  };

  gload(jbase);
  lwrite(0);
  unsigned int mk_cur = mp[(size_t)(jbase >> 6) * 64];
  __syncthreads();

  for (int it = 0; it < NIT; ++it) {
    const int cur = it & 1;
    const int j0 = jbase + it * TJ;
    unsigned int mk_next = 0;
    if (it + 1 < NIT) {
      gload(j0 + TJ);
      mk_next = mp[(size_t)((j0 + TJ) >> 6) * 64];
    }

    // scores from LDS s2
    float s2r[NH * 8];
    *(float4*)&s2r[0] = *(const float4*)&s2s[j0 + quad * 8];
    *(float4*)&s2r[4] = *(const float4*)&s2s[j0 + quad * 8 + 4];
    if constexpr (NH == 2) {
      *(float4*)&s2r[8]  = *(const float4*)&s2s[j0 + 32 + quad * 8];
      *(float4*)&s2r[12] = *(const float4*)&s2s[j0 + 32 + quad * 8 + 4];
    }

    f16x8 afr[NH];
    #pragma unroll
    for (int h = 0; h < NH; ++h) {
      unsigned int mbyte;
      if constexpr (EPI == 0) mbyte = (mk_cur >> (h * 8)) & 0xffu;
      else                    mbyte = (mk_cur >> (8 * ((j0 >> 5) & 1))) & 0xffu;
      float wgt[8];
      #pragma unroll
      for (int k = 0; k < 8; ++k) {
        float t0 = p + s2r[h * 8 + k];
        float t1 = fmaf(SLOPE_, t0, cq);
        float tm = fmaxf(t0, t1);
        float e = __builtin_amdgcn_exp2f(tm);
        int sel = (int)(mbyte << (31 - k)) >> 31;
        union { float f; int i; } u; u.f = e; u.i &= sel;
        wgt[k] = u.f;
      }
      afr[h] = pack8(wgt);
    }

    const __fp16* vb = &vbuf[jq][cur][0];
    #pragma unroll
    for (int h = 0; h < NH; ++h) {
      acc5 = __builtin_amdgcn_mfma_f32_16x16x32_f16(afr[h], ones, acc5, 0, 0, 0);
      #pragma unroll
      for (int t = 0; t < 4; ++t) {
        f16x8 bf = *(const f16x8*)(vb + h * 2048 + t * 512 + l * 8);
        acc[t] = __builtin_amdgcn_mfma_f32_16x16x32_f16(afr[h], bf, acc[t], 0, 0, 0);
      }
    }

    if (it + 1 < NIT) {
      lwrite(cur ^ 1);
      mk_cur = mk_next;
    }
    __syncthreads();
  }

  // ---- combine partials across j-chunks (overlay LDS; loop barrier done) ----
  auto pacc = (float(*)[NRG][16][64])(&vbuf[0][0][0]);
  auto pls  = (float(*)[NRG][16])(&s2s[0]);
  if (jq > 0) {
    #pragma unroll
    for (int t = 0; t < 4; ++t)
      #pragma unroll
      for (int r = 0; r < 4; ++r)
        pacc[jq - 1][rowg][quad * 4 + r][t * 16 + c15] = acc[t][r];
    if (c15 == 0) {
      #pragma unroll
      for (int r = 0; r < 4; ++r)
        pls[jq - 1][rowg][quad * 4 + r] = acc5[r];
    }
  }
  __syncthreads();
  if (jq == 0) {
    float Lrow[4];
    #pragma unroll
    for (int r = 0; r < 4; ++r) Lrow[r] = acc5[r];
    #pragma unroll
    for (int q = 0; q < NJQ - 1; ++q) {
      #pragma unroll
      for (int t = 0; t < 4; ++t)
        #pragma unroll
        for (int r = 0; r < 4; ++r)
          acc[t][r] += pacc[q][rowg][quad * 4 + r][t * 16 + c15];
      #pragma unroll
      for (int r = 0; r < 4; ++r) Lrow[r] += pls[q][rowg][quad * 4 + r];
    }
    float lr[4];
    #pragma unroll
    for (int r = 0; r < 4; ++r) lr[r] = 1.f / Lrow[r];

    #pragma unroll
    for (int t = 0; t < 4; ++t) {
      const float bv = bias[colbase + t * 16 + c15];
      #pragma unroll
      for (int r = 0; r < 4; ++r) {
        const int i = i0w + quad * 4 + r;
        float v = acc[t][r] * lr[r] + bv;
        if constexpr (EPI == 0) {
          v = (v > 0.f) ? v : expm1f(v);      // elu
          ((__fp16*)outp)[(size_t)(b * N_ + i) * OSTR + colbase + t * 16 + c15] = (__fp16)v;
        } else {
          v = fmaxf(v, 0.f);                  // relu(elu)=relu
          ((float*)outp)[(size_t)(b * N_ + i) * OSTR + colbase + t * 16 + c15] = v;
        }
      }
    }
  }
}

// ---------------------------------------------------------------------------
extern "C" void kernel_launch(void* const* d_in, const int* in_sizes, int n_in,
                              void* d_out, int out_size, void* d_ws, size_t ws_size,
                              hipStream_t stream) {
  const float* x   = (const float*)d_in[0];
  const int*   adj = (const int*)d_in[1];
  const float* Wh  = (const float*)d_in[2];
  const float* ah  = (const float*)d_in[3];
  const float* bh  = (const float*)d_in[4];
  const float* Wo  = (const float*)d_in[5];
  const float* ao  = (const float*)d_in[6];
  const float* bo  = (const float*)d_in[7];
  float* out = (float*)d_out;

  float* ws   = (float*)d_ws;
  float* s1h  = ws;                                   // B*8*N
  float* s2h  = s1h  + (size_t)B_ * NHEADS_ * N_;
  float* s1o  = s2h  + (size_t)B_ * NHEADS_ * N_;     // B*N
  float* s2o  = s1o  + (size_t)B_ * N_;
  float* s2mh = s2o  + (size_t)B_ * N_;               // 32 (pad 64)
  float* s2mo = s2mh + 64;                            // 4 (pad 64)
  __fp16* g1  = (__fp16*)(s2mo + 64);                 // B*N*512 f16 (8 MB)
  __fp16* hB1 = g1  + (size_t)B_ * N_ * 512;          // 8 MB
  __fp16* hB2 = hB1 + (size_t)B_ * NHEADS_ * N_ * 64; // 2 MB
  __fp16* WhB = hB2 + (size_t)B_ * N_ * 128;          // 256 KB
  __fp16* WoB = WhB + (size_t)8 * 256 * 64;           // 128 KB
  unsigned short* mask2 = (unsigned short*)(WoB + (size_t)512 * 128); // 2 MB

  k_packmask<<<(B_ * 128 * 32 * 64) / 256, 256, 0, stream>>>(adj, mask2);
  k_prepwh<<<64, 256, 0, stream>>>(Wh, WhB);
  k_prepwo<<<32, 256, 0, stream>>>(Wo, WoB);
  k_gemm1<<<B_ * (N_ / 16), 256, 0, stream>>>(x, WhB, ah, hB1, s1h, s2h);
  k_rowmax<<<B_ * NHEADS_, 256, 0, stream>>>(s2h, s2mh);
  k_att<0><<<B_ * NHEADS_ * (N_ / 64), 512, 0, stream>>>(
      hB1, s1h, s2h, s2mh, mask2, bh, (void*)g1);
  k_gemm2<<<B_ * (N_ / 16), 256, 0, stream>>>(g1, WoB, ao, hB2, s1o, s2o);
  k_rowmax<<<B_, 256, 0, stream>>>(s2o, s2mo);
  k_att<1><<<B_ * 2 * (N_ / 32), 512, 0, stream>>>(
      hB2, s1o, s2o, s2mo, mask2, bo, (void*)out);
}

// Round 12
// 208.894 us; speedup vs baseline: 1.1757x; 1.1622x over previous
//
#include <hip/hip_runtime.h>

constexpr int B_ = 4;
constexpr int N_ = 2048;
constexpr int NFEAT_ = 256;
constexpr int NHEADS_ = 8;
constexpr float SLOPE_ = 0.1f;
constexpr float L2E = 1.4426950408889634f;   // log2(e)

typedef __attribute__((ext_vector_type(8))) __fp16 f16x8;
typedef __attribute__((ext_vector_type(2))) __fp16 f16x2;
typedef __attribute__((ext_vector_type(4))) float f32x4;

__device__ __forceinline__ f16x8 pack8(const float* v) {
  union { f16x2 h2[4]; f16x8 h8; } u;
  u.h2[0] = __builtin_amdgcn_cvt_pkrtz(v[0], v[1]);
  u.h2[1] = __builtin_amdgcn_cvt_pkrtz(v[2], v[3]);
  u.h2[2] = __builtin_amdgcn_cvt_pkrtz(v[4], v[5]);
  u.h2[3] = __builtin_amdgcn_cvt_pkrtz(v[6], v[7]);
  return u.h8;
}

// ---------------------------------------------------------------------------
// adj -> fragment-ordered mask: mask2[b][i16grp(128)][jt(32)][lane(64)] ushort
// ---------------------------------------------------------------------------
__global__ __launch_bounds__(256) void k_packmask(
    const int* __restrict__ adj, unsigned short* __restrict__ mask2)
{
  const int l = threadIdx.x & 63;
  const size_t gw = ((size_t)blockIdx.x * 256 + threadIdx.x) >> 6;
  const int jt = (int)(gw & 31);
  const int ig16 = (int)((gw >> 5) & 127);
  const int b = (int)(gw >> 12);
  const int q = l >> 4, c15 = l & 15;

  const int* base = adj + ((size_t)b * N_ + ig16 * 16) * N_ + jt * 64 + l;
  unsigned int msk = 0;
  #pragma unroll
  for (int r = 0; r < 16; ++r) {
    int a = base[(size_t)r * N_];
    unsigned long long bal = __ballot(a > 0);
    unsigned int v = (unsigned int)((bal >> (q * 8)) & 0xffull)
                   | ((unsigned int)((bal >> (q * 8 + 32)) & 0xffull) << 8);
    if (r == c15) msk = v;
  }
  mask2[gw * 64 + l] = (unsigned short)msk;
}

// ---------------------------------------------------------------------------
// row max over N_ (for s2max)
// ---------------------------------------------------------------------------
__global__ __launch_bounds__(256) void k_rowmax(
    const float* __restrict__ src, float* __restrict__ dst)
{
  int row = blockIdx.x, t = threadIdx.x;
  const float* p = src + (size_t)row * N_;
  float m = -INFINITY;
  #pragma unroll
  for (int k = 0; k < N_ / 256; ++k) m = fmaxf(m, p[t + k * 256]);
  #pragma unroll
  for (int off = 1; off < 64; off <<= 1) m = fmaxf(m, __shfl_xor(m, off, 64));
  __shared__ float sm[4];
  if ((t & 63) == 0) sm[t >> 6] = m;
  __syncthreads();
  if (t == 0) dst[row] = fmaxf(fmaxf(sm[0], sm[1]), fmaxf(sm[2], sm[3]));
}

// ---------------------------------------------------------------------------
// Wh f32 [8][256][64] -> WhB f16 MFMA-B-frag [h][ks 8][ft 4][lane 64][8]
// ---------------------------------------------------------------------------
__global__ __launch_bounds__(256) void k_prepwh(
    const float* __restrict__ Wh, __fp16* __restrict__ WhB)
{
  int l = threadIdx.x & 63;
  int s = (int)((blockIdx.x * 256 + threadIdx.x) >> 6);   // 0..255
  int h = s >> 5, ks = (s >> 2) & 7, ft = s & 3;
  const float* src = Wh + ((size_t)h * 256 + ks * 32 + (l >> 4) * 8) * 64 + ft * 16 + (l & 15);
  float v[8];
  #pragma unroll
  for (int j = 0; j < 8; ++j) v[j] = src[(size_t)j * 64];
  *(f16x8*)(WhB + (size_t)s * 512 + l * 8) = pack8(v);
}

// ---------------------------------------------------------------------------
// Wo f32 [512][128] -> WoB f16 B-frag [ks 16][ft 8][lane 64][8]
// ---------------------------------------------------------------------------
__global__ __launch_bounds__(256) void k_prepwo(
    const float* __restrict__ Wo, __fp16* __restrict__ WoB)
{
  int l = threadIdx.x & 63;
  int s = (int)((blockIdx.x * 256 + threadIdx.x) >> 6);   // 0..127
  int ks = s >> 3, ft = s & 7;
  const float* src = Wo + ((size_t)ks * 32 + (l >> 4) * 8) * 128 + ft * 16 + (l & 15);
  float v[8];
  #pragma unroll
  for (int j = 0; j < 8; ++j) v[j] = src[(size_t)j * 128];
  *(f16x8*)(WoB + (size_t)s * 512 + l * 8) = pack8(v);
}

// ---------------------------------------------------------------------------
// GEMM1 (MFMA): block = 16 n-rows x ALL 512 f (8 heads), 256 thr = 4 waves.
// ---------------------------------------------------------------------------
__global__ __launch_bounds__(256, 4) void k_gemm1(
    const float* __restrict__ x, const __fp16* __restrict__ WhB,
    const float* __restrict__ ah,
    __fp16* __restrict__ hB1, float* __restrict__ s1h, float* __restrict__ s2h)
{
  constexpr int XP = 264;
  __shared__ __fp16 xs[16 * XP];
  __shared__ __fp16 hT[512 * 16];

  const int t = threadIdx.x;
  const int bid = blockIdx.x;
  const int b = bid >> 7;
  const int n0 = (bid & 127) * 16;

  {  // stage x -> f16
    int r = t >> 4, k0 = (t & 15) * 16;
    const float* src = x + ((size_t)(b * N_) + n0 + r) * NFEAT_ + k0;
    float v0[8], v1[8];
    *(float4*)&v0[0] = *(const float4*)(src);
    *(float4*)&v0[4] = *(const float4*)(src + 4);
    *(float4*)&v1[0] = *(const float4*)(src + 8);
    *(float4*)&v1[4] = *(const float4*)(src + 12);
    *(f16x8*)&xs[r * XP + k0] = pack8(v0);
    *(f16x8*)&xs[r * XP + k0 + 8] = pack8(v1);
  }
  __syncthreads();

  const int w = t >> 6, l = t & 63;
  const int quad = l >> 4, c15 = l & 15;

  f32x4 acc[8];
  #pragma unroll
  for (int i = 0; i < 8; ++i) acc[i] = (f32x4){0.f, 0.f, 0.f, 0.f};

  for (int ks = 0; ks < 8; ++ks) {
    f16x8 af = *(const f16x8*)&xs[c15 * XP + ks * 32 + quad * 8];
    #pragma unroll
    for (int tt = 0; tt < 8; ++tt) {
      int hl = tt >> 2, ft = tt & 3;
      f16x8 bf = *(const f16x8*)(WhB +
          ((((size_t)(2 * w + hl) * 8 + ks) * 4 + ft) * 512) + l * 8);
      acc[tt] = __builtin_amdgcn_mfma_f32_16x16x32_f16(af, bf, acc[tt], 0, 0, 0);
    }
  }

  #pragma unroll
  for (int hl = 0; hl < 2; ++hl) {
    int head = 2 * w + hl;
    float a1v[4], a2v[4];
    #pragma unroll
    for (int ft = 0; ft < 4; ++ft) {
      a1v[ft] = ah[head * 128 + ft * 16 + c15] * L2E;
      a2v[ft] = ah[head * 128 + 64 + ft * 16 + c15] * L2E;
    }
    #pragma unroll
    for (int r = 0; r < 4; ++r) {
      float v1 = 0.f, v2 = 0.f;
      #pragma unroll
      for (int ft = 0; ft < 4; ++ft) {
        v1 = fmaf(acc[hl * 4 + ft][r], a1v[ft], v1);
        v2 = fmaf(acc[hl * 4 + ft][r], a2v[ft], v2);
      }
      #pragma unroll
      for (int off = 1; off < 16; off <<= 1) {
        v1 += __shfl_xor(v1, off, 64);
        v2 += __shfl_xor(v2, off, 64);
      }
      if (c15 == 0) {
        s1h[(size_t)(b * NHEADS_ + head) * N_ + n0 + quad * 4 + r] = v1;
        s2h[(size_t)(b * NHEADS_ + head) * N_ + n0 + quad * 4 + r] = v2;
      }
    }
  }

  #pragma unroll
  for (int tt = 0; tt < 8; ++tt) {
    int f = (2 * w + (tt >> 2)) * 64 + (tt & 3) * 16 + c15;
    #pragma unroll
    for (int r = 0; r < 4; ++r)
      hT[f * 16 + quad * 4 + r] = (__fp16)acc[tt][r];
  }
  __syncthreads();

  const int base_oct = (n0 >> 3) & 3;
  #pragma unroll
  for (int q = 0; q < 4; ++q) {
    int s = t + q * 256;
    int c15v = s & 15, oct = (s >> 4) & 1, ft = (s >> 5) & 3, head = s >> 7;
    f16x8 v = *(const f16x8*)&hT[(head * 64 + ft * 16 + c15v) * 16 + oct * 8];
    int lane0 = (base_oct + oct) * 16 + c15v;
    *(f16x8*)(hB1 +
        ((((size_t)(b * NHEADS_ + head) * 64 + (n0 >> 5)) * 4 + ft) * 512) + lane0 * 8) = v;
  }
}

// ---------------------------------------------------------------------------
// GEMM2 (MFMA): block = 16 n-rows x 128 f, 256 thr = 4 waves.
// ---------------------------------------------------------------------------
__global__ __launch_bounds__(256, 4) void k_gemm2(
    const __fp16* __restrict__ g1, const __fp16* __restrict__ WoB,
    const float* __restrict__ ao,
    __fp16* __restrict__ hB2, float* __restrict__ s1o, float* __restrict__ s2o)
{
  constexpr int GP = 520;
  __shared__ __fp16 gs[16 * GP];
  __shared__ __fp16 hT[128 * 16];
  __shared__ float sd1[4][16], sd2[4][16];

  const int t = threadIdx.x;
  const int bid = blockIdx.x;
  const int b = bid >> 7;
  const int n0 = (bid & 127) * 16;

  {
    int r = t >> 4, k0 = (t & 15) * 32;
    const __fp16* src = g1 + ((size_t)(b * N_) + n0 + r) * 512 + k0;
    #pragma unroll
    for (int i = 0; i < 4; ++i)
      *(f16x8*)&gs[r * GP + k0 + i * 8] = *(const f16x8*)(src + i * 8);
  }
  __syncthreads();

  const int w = t >> 6, l = t & 63;
  const int quad = l >> 4, c15 = l & 15;

  f32x4 acc[2];
  acc[0] = (f32x4){0.f, 0.f, 0.f, 0.f};
  acc[1] = (f32x4){0.f, 0.f, 0.f, 0.f};

  for (int ks = 0; ks < 16; ++ks) {
    f16x8 af = *(const f16x8*)&gs[c15 * GP + ks * 32 + quad * 8];
    #pragma unroll
    for (int tt = 0; tt < 2; ++tt) {
      int ft = 2 * w + tt;
      f16x8 bf = *(const f16x8*)(WoB + (((size_t)ks * 8 + ft) * 512) + l * 8);
      acc[tt] = __builtin_amdgcn_mfma_f32_16x16x32_f16(af, bf, acc[tt], 0, 0, 0);
    }
  }

  {
    float a1v[2], a2v[2];
    #pragma unroll
    for (int tt = 0; tt < 2; ++tt) {
      int f = (2 * w + tt) * 16 + c15;
      a1v[tt] = ao[f] * L2E;
      a2v[tt] = ao[128 + f] * L2E;
    }
    #pragma unroll
    for (int r = 0; r < 4; ++r) {
      float v1 = acc[0][r] * a1v[0] + acc[1][r] * a1v[1];
      float v2 = acc[0][r] * a2v[0] + acc[1][r] * a2v[1];
      #pragma unroll
      for (int off = 1; off < 16; off <<= 1) {
        v1 += __shfl_xor(v1, off, 64);
        v2 += __shfl_xor(v2, off, 64);
      }
      if (c15 == 0) { sd1[w][quad * 4 + r] = v1; sd2[w][quad * 4 + r] = v2; }
    }
  }

  #pragma unroll
  for (int tt = 0; tt < 2; ++tt) {
    int f = (2 * w + tt) * 16 + c15;
    #pragma unroll
    for (int r = 0; r < 4; ++r)
      hT[f * 16 + quad * 4 + r] = (__fp16)acc[tt][r];
  }
  __syncthreads();

  if (t < 16)
    s1o[(size_t)b * N_ + n0 + t] = sd1[0][t] + sd1[1][t] + sd1[2][t] + sd1[3][t];
  else if (t < 32) {
    int rr = t - 16;
    s2o[(size_t)b * N_ + n0 + rr] = sd2[0][rr] + sd2[1][rr] + sd2[2][rr] + sd2[3][rr];
  }

  {
    int c15v = t & 15, oct = (t >> 4) & 1, ft = t >> 5;
    f16x8 v = *(const f16x8*)&hT[(ft * 16 + c15v) * 16 + oct * 8];
    int base_oct = (n0 >> 3) & 3;
    int lane0 = (base_oct + oct) * 16 + c15v;
    *(f16x8*)(hB2 +
        (((size_t)(b * 64 + (n0 >> 5)) * 8 + ft) * 512) + lane0 * 8) = v;
  }
}

// ---------------------------------------------------------------------------
// MFMA flash attention, LDS-staged V tiles via ASYNC global_load_lds (w=16):
// no staging VGPRs at all (R10/R11 spilled stg[] -> 169 MB scratch writes).
// Per iteration: issue next tile's DMA loads (async, vmcnt), compute current
// tile from LDS, __syncthreads() drains. Global addr = base + lane*16,
// LDS dest = wave-uniform base + lane*16 (m104 constraint satisfied).
// ---------------------------------------------------------------------------
template<int EPI>
__global__ __launch_bounds__(512, 4) void k_att(
    const __fp16* __restrict__ hB, const float* __restrict__ s1,
    const float* __restrict__ s2, const float* __restrict__ s2max,
    const unsigned short* __restrict__ mask2,
    const float* __restrict__ bias, void* __restrict__ outp)
{
  constexpr int H    = (EPI == 0) ? 8 : 1;
  constexpr int NFT  = (EPI == 0) ? 4 : 8;
  constexpr int KSTR = NFT * 512;              // f16 per kstep
  constexpr int OSTR = (EPI == 0) ? 512 : 128;
  constexpr int NRG  = (EPI == 0) ? 4 : 2;
  constexpr int NJQ  = 8 / NRG;
  constexpr int JLEN = N_ / NJQ;
  constexpr int TJ   = (EPI == 0) ? 64 : 32;
  constexpr int NIT  = JLEN / TJ;
  constexpr int IBLK = NRG * 16;
  constexpr int NH   = TJ / 32;                // kstep-halves per tile
  constexpr int TILE = TJ * 64;                // f16 per tile (per fs view)
  constexpr int CPT  = (TILE * 2) / (NRG * 64 * 16);  // 16B DMA ops per thread

  __shared__ __fp16 vbuf[NJQ][2][TILE];
  __shared__ float s2s[N_];

  const int tid = threadIdx.x;
  const int w = tid >> 6, l = tid & 63;
  const int quad = l >> 4, c15 = l & 15;
  const int rowg = w % NRG, jq = w / NRG;
  const int tc = rowg * 64 + l;                // thread index within chunk

  int idx = blockIdx.x;
  const int ig = idx % (N_ / IBLK); idx /= (N_ / IBLK);
  int head = 0, fs = 0;
  if constexpr (EPI == 0) { head = idx % 8; idx /= 8; }
  else                    { fs = idx % 2; idx /= 2; }
  const int b = idx;

  const int i0w = ig * IBLK + rowg * 16;
  const int colbase = (EPI == 0) ? head * 64 : fs * 64;

  const float* s1p = s1 + (size_t)(b * H + head) * N_;
  const float* s2p = s2 + (size_t)(b * H + head) * N_;
  const char* hBp = (const char*)(hB + (size_t)(b * H + head) * (N_ / 32) * KSTR
                                  + (EPI == 0 ? 0 : fs * 2048));
  const unsigned short* mp = mask2 + ((size_t)(b * 128 + (i0w >> 4)) * 32) * 64 + l;

  // stage s2 row into LDS (512 thr x float4 = 2048)
  *(float4*)&s2s[tid * 4] = *(const float4*)(s2p + tid * 4);

  const float s1v = s1p[i0w + c15];
  const float zm = s1v + s2max[b * H + head];
  const float m = fmaxf(zm, SLOPE_ * zm);      // exact unmasked row max
  const float p = s1v - m;
  const float cq = (SLOPE_ - 1.f) * m;

  f16x8 ones;
  #pragma unroll
  for (int i = 0; i < 8; ++i) ones[i] = (__fp16)1.0f;

  f32x4 acc[4], acc5;
  #pragma unroll
  for (int t = 0; t < 4; ++t) acc[t] = (f32x4){0.f, 0.f, 0.f, 0.f};
  acc5 = (f32x4){0.f, 0.f, 0.f, 0.f};

  const int jbase = jq * JLEN;

  // async DMA staging: global byte = tile_base + off, LDS byte = slot + off,
  // off = (tc + c*NRG*64)*16; (off - l*16) is wave-uniform as required.
  auto stage = [&](int j0, int slot) {
    const char* srcb = hBp + (size_t)(j0 >> 5) * (KSTR * 2);
    #pragma unroll
    for (int c = 0; c < CPT; ++c) {
      int off = (tc + c * NRG * 64) * 16;
      const char* g = srcb + off;
      char* d = (char*)&vbuf[jq][slot][0] + (off - l * 16);
      __builtin_amdgcn_global_load_lds(
          (const __attribute__((address_space(1))) unsigned int*)g,
          (__attribute__((address_space(3))) unsigned int*)d, 16, 0, 0);
    }
  };

  stage(jbase, 0);
  unsigned int mk_cur = mp[(size_t)(jbase >> 6) * 64];
  __syncthreads();                             // drains DMA for slot 0

  for (int it = 0; it < NIT; ++it) {
    const int cur = it & 1;
    const int j0 = jbase + it * TJ;
    unsigned int mk_next = 0;
    if (it + 1 < NIT) {
      stage(j0 + TJ, cur ^ 1);                 // async, overlaps compute below
      mk_next = mp[(size_t)((j0 + TJ) >> 6) * 64];
    }

    // scores from LDS s2
    float s2r[NH * 8];
    *(float4*)&s2r[0] = *(const float4*)&s2s[j0 + quad * 8];
    *(float4*)&s2r[4] = *(const float4*)&s2s[j0 + quad * 8 + 4];
    if constexpr (NH == 2) {
      *(float4*)&s2r[8]  = *(const float4*)&s2s[j0 + 32 + quad * 8];
      *(float4*)&s2r[12] = *(const float4*)&s2s[j0 + 32 + quad * 8 + 4];
    }

    f16x8 afr[NH];
    #pragma unroll
    for (int h = 0; h < NH; ++h) {
      unsigned int mbyte;
      if constexpr (EPI == 0) mbyte = (mk_cur >> (h * 8)) & 0xffu;
      else                    mbyte = (mk_cur >> (8 * ((j0 >> 5) & 1))) & 0xffu;
      float wgt[8];
      #pragma unroll
      for (int k = 0; k < 8; ++k) {
        float t0 = p + s2r[h * 8 + k];
        float t1 = fmaf(SLOPE_, t0, cq);
        float tm = fmaxf(t0, t1);
        float e = __builtin_amdgcn_exp2f(tm);
        int sel = (int)(mbyte << (31 - k)) >> 31;
        union { float f; int i; } u; u.f = e; u.i &= sel;
        wgt[k] = u.f;
      }
      afr[h] = pack8(wgt);
    }

    const __fp16* vb = &vbuf[jq][cur][0];
    #pragma unroll
    for (int h = 0; h < NH; ++h) {
      acc5 = __builtin_amdgcn_mfma_f32_16x16x32_f16(afr[h], ones, acc5, 0, 0, 0);
      #pragma unroll
      for (int t = 0; t < 4; ++t) {
        f16x8 bf = *(const f16x8*)(vb + h * 2048 + t * 512 + l * 8);
        acc[t] = __builtin_amdgcn_mfma_f32_16x16x32_f16(afr[h], bf, acc[t], 0, 0, 0);
      }
    }

    mk_cur = mk_next;
    __syncthreads();                           // drains next DMA + LDS reads
  }

  // ---- combine partials across j-chunks (overlay LDS; loop barrier done) ----
  auto pacc = (float(*)[NRG][16][64])(&vbuf[0][0][0]);
  auto pls  = (float(*)[NRG][16])(&s2s[0]);
  if (jq > 0) {
    #pragma unroll
    for (int t = 0; t < 4; ++t)
      #pragma unroll
      for (int r = 0; r < 4; ++r)
        pacc[jq - 1][rowg][quad * 4 + r][t * 16 + c15] = acc[t][r];
    if (c15 == 0) {
      #pragma unroll
      for (int r = 0; r < 4; ++r)
        pls[jq - 1][rowg][quad * 4 + r] = acc5[r];
    }
  }
  __syncthreads();
  if (jq == 0) {
    float Lrow[4];
    #pragma unroll
    for (int r = 0; r < 4; ++r) Lrow[r] = acc5[r];
    #pragma unroll
    for (int q = 0; q < NJQ - 1; ++q) {
      #pragma unroll
      for (int t = 0; t < 4; ++t)
        #pragma unroll
        for (int r = 0; r < 4; ++r)
          acc[t][r] += pacc[q][rowg][quad * 4 + r][t * 16 + c15];
      #pragma unroll
      for (int r = 0; r < 4; ++r) Lrow[r] += pls[q][rowg][quad * 4 + r];
    }
    float lr[4];
    #pragma unroll
    for (int r = 0; r < 4; ++r) lr[r] = 1.f / Lrow[r];

    #pragma unroll
    for (int t = 0; t < 4; ++t) {
      const float bv = bias[colbase + t * 16 + c15];
      #pragma unroll
      for (int r = 0; r < 4; ++r) {
        const int i = i0w + quad * 4 + r;
        float v = acc[t][r] * lr[r] + bv;
        if constexpr (EPI == 0) {
          v = (v > 0.f) ? v : expm1f(v);      // elu
          ((__fp16*)outp)[(size_t)(b * N_ + i) * OSTR + colbase + t * 16 + c15] = (__fp16)v;
        } else {
          v = fmaxf(v, 0.f);                  // relu(elu)=relu
          ((float*)outp)[(size_t)(b * N_ + i) * OSTR + colbase + t * 16 + c15] = v;
        }
      }
    }
  }
}

// ---------------------------------------------------------------------------
extern "C" void kernel_launch(void* const* d_in, const int* in_sizes, int n_in,
                              void* d_out, int out_size, void* d_ws, size_t ws_size,
                              hipStream_t stream) {
  const float* x   = (const float*)d_in[0];
  const int*   adj = (const int*)d_in[1];
  const float* Wh  = (const float*)d_in[2];
  const float* ah  = (const float*)d_in[3];
  const float* bh  = (const float*)d_in[4];
  const float* Wo  = (const float*)d_in[5];
  const float* ao  = (const float*)d_in[6];
  const float* bo  = (const float*)d_in[7];
  float* out = (float*)d_out;

  float* ws   = (float*)d_ws;
  float* s1h  = ws;                                   // B*8*N
  float* s2h  = s1h  + (size_t)B_ * NHEADS_ * N_;
  float* s1o  = s2h  + (size_t)B_ * NHEADS_ * N_;     // B*N
  float* s2o  = s1o  + (size_t)B_ * N_;
  float* s2mh = s2o  + (size_t)B_ * N_;               // 32 (pad 64)
  float* s2mo = s2mh + 64;                            // 4 (pad 64)
  __fp16* g1  = (__fp16*)(s2mo + 64);                 // B*N*512 f16 (8 MB)
  __fp16* hB1 = g1  + (size_t)B_ * N_ * 512;          // 8 MB
  __fp16* hB2 = hB1 + (size_t)B_ * NHEADS_ * N_ * 64; // 2 MB
  __fp16* WhB = hB2 + (size_t)B_ * N_ * 128;          // 256 KB
  __fp16* WoB = WhB + (size_t)8 * 256 * 64;           // 128 KB
  unsigned short* mask2 = (unsigned short*)(WoB + (size_t)512 * 128); // 2 MB

  k_packmask<<<(B_ * 128 * 32 * 64) / 256, 256, 0, stream>>>(adj, mask2);
  k_prepwh<<<64, 256, 0, stream>>>(Wh, WhB);
  k_prepwo<<<32, 256, 0, stream>>>(Wo, WoB);
  k_gemm1<<<B_ * (N_ / 16), 256, 0, stream>>>(x, WhB, ah, hB1, s1h, s2h);
  k_rowmax<<<B_ * NHEADS_, 256, 0, stream>>>(s2h, s2mh);
  k_att<0><<<B_ * NHEADS_ * (N_ / 64), 512, 0, stream>>>(
      hB1, s1h, s2h, s2mh, mask2, bh, (void*)g1);
  k_gemm2<<<B_ * (N_ / 16), 256, 0, stream>>>(g1, WoB, ao, hB2, s1o, s2o);
  k_rowmax<<<B_, 256, 0, stream>>>(s2o, s2mo);
  k_att<1><<<B_ * 2 * (N_ / 32), 512, 0, stream>>>(
      hB2, s1o, s2o, s2mo, mask2, bo, (void*)out);
}

// Round 13
// 203.072 us; speedup vs baseline: 1.2094x; 1.0287x over previous
//
#include <hip/hip_runtime.h>

constexpr int B_ = 4;
constexpr int N_ = 2048;
constexpr int NFEAT_ = 256;
constexpr int NHEADS_ = 8;
constexpr float SLOPE_ = 0.1f;
constexpr float L2E = 1.4426950408889634f;   // log2(e)

typedef __attribute__((ext_vector_type(8))) __fp16 f16x8;
typedef __attribute__((ext_vector_type(4))) __fp16 f16x4;
typedef __attribute__((ext_vector_type(2))) __fp16 f16x2;
typedef __attribute__((ext_vector_type(4))) float f32x4;

__device__ __forceinline__ f16x8 pack8(const float* v) {
  union { f16x2 h2[4]; f16x8 h8; } u;
  u.h2[0] = __builtin_amdgcn_cvt_pkrtz(v[0], v[1]);
  u.h2[1] = __builtin_amdgcn_cvt_pkrtz(v[2], v[3]);
  u.h2[2] = __builtin_amdgcn_cvt_pkrtz(v[4], v[5]);
  u.h2[3] = __builtin_amdgcn_cvt_pkrtz(v[6], v[7]);
  return u.h8;
}
__device__ __forceinline__ f16x4 pack4(float a, float b, float c, float d) {
  union { f16x2 h2[2]; f16x4 h4; } u;
  u.h2[0] = __builtin_amdgcn_cvt_pkrtz(a, b);
  u.h2[1] = __builtin_amdgcn_cvt_pkrtz(c, d);
  return u.h4;
}

// ---------------------------------------------------------------------------
// Fused prep: blocks [0,4096) packmask; [4096,4160) prepWh; [4160,4192) prepWo
// mask2[b][i16grp(128)][jt(32)][lane(64)] ushort (fragment-ordered).
// WhB f16 B-frag [h][ks 8][ft 4][lane][8]; WoB [ks 16][ft 8][lane][8].
// ---------------------------------------------------------------------------
__global__ __launch_bounds__(256) void k_prep(
    const int* __restrict__ adj, unsigned short* __restrict__ mask2,
    const float* __restrict__ Wh, __fp16* __restrict__ WhB,
    const float* __restrict__ Wo, __fp16* __restrict__ WoB)
{
  const int bid = blockIdx.x;
  const int l = threadIdx.x & 63;
  if (bid < 4096) {
    const size_t gw = ((size_t)bid * 256 + threadIdx.x) >> 6;
    const int jt = (int)(gw & 31);
    const int ig16 = (int)((gw >> 5) & 127);
    const int b = (int)(gw >> 12);
    const int q = l >> 4, c15 = l & 15;
    const int* base = adj + ((size_t)b * N_ + ig16 * 16) * N_ + jt * 64 + l;
    unsigned int msk = 0;
    #pragma unroll
    for (int r = 0; r < 16; ++r) {
      int a = base[(size_t)r * N_];
      unsigned long long bal = __ballot(a > 0);
      unsigned int v = (unsigned int)((bal >> (q * 8)) & 0xffull)
                     | ((unsigned int)((bal >> (q * 8 + 32)) & 0xffull) << 8);
      if (r == c15) msk = v;
    }
    mask2[gw * 64 + l] = (unsigned short)msk;
  } else if (bid < 4160) {
    int s = (int)(((bid - 4096) * 256 + threadIdx.x) >> 6);   // 0..255
    int h = s >> 5, ks = (s >> 2) & 7, ft = s & 3;
    const float* src = Wh + ((size_t)h * 256 + ks * 32 + (l >> 4) * 8) * 64 + ft * 16 + (l & 15);
    float v[8];
    #pragma unroll
    for (int j = 0; j < 8; ++j) v[j] = src[(size_t)j * 64];
    *(f16x8*)(WhB + (size_t)s * 512 + l * 8) = pack8(v);
  } else {
    int s = (int)(((bid - 4160) * 256 + threadIdx.x) >> 6);   // 0..127
    int ks = s >> 3, ft = s & 7;
    const float* src = Wo + ((size_t)ks * 32 + (l >> 4) * 8) * 128 + ft * 16 + (l & 15);
    float v[8];
    #pragma unroll
    for (int j = 0; j < 8; ++j) v[j] = src[(size_t)j * 128];
    *(f16x8*)(WoB + (size_t)s * 512 + l * 8) = pack8(v);
  }
}

// ---------------------------------------------------------------------------
// GEMM1 (MFMA): block = 16 n-rows x ALL 512 f (8 heads), 256 thr = 4 waves.
// ---------------------------------------------------------------------------
__global__ __launch_bounds__(256, 4) void k_gemm1(
    const float* __restrict__ x, const __fp16* __restrict__ WhB,
    const float* __restrict__ ah,
    __fp16* __restrict__ hB1, float* __restrict__ s1h, float* __restrict__ s2h)
{
  constexpr int XP = 264;
  __shared__ __fp16 xs[16 * XP];
  __shared__ __fp16 hT[512 * 16];

  const int t = threadIdx.x;
  const int bid = blockIdx.x;
  const int b = bid >> 7;
  const int n0 = (bid & 127) * 16;

  {  // stage x -> f16
    int r = t >> 4, k0 = (t & 15) * 16;
    const float* src = x + ((size_t)(b * N_) + n0 + r) * NFEAT_ + k0;
    float v0[8], v1[8];
    *(float4*)&v0[0] = *(const float4*)(src);
    *(float4*)&v0[4] = *(const float4*)(src + 4);
    *(float4*)&v1[0] = *(const float4*)(src + 8);
    *(float4*)&v1[4] = *(const float4*)(src + 12);
    *(f16x8*)&xs[r * XP + k0] = pack8(v0);
    *(f16x8*)&xs[r * XP + k0 + 8] = pack8(v1);
  }
  __syncthreads();

  const int w = t >> 6, l = t & 63;
  const int quad = l >> 4, c15 = l & 15;

  f32x4 acc[8];
  #pragma unroll
  for (int i = 0; i < 8; ++i) acc[i] = (f32x4){0.f, 0.f, 0.f, 0.f};

  for (int ks = 0; ks < 8; ++ks) {
    f16x8 af = *(const f16x8*)&xs[c15 * XP + ks * 32 + quad * 8];
    #pragma unroll
    for (int tt = 0; tt < 8; ++tt) {
      int hl = tt >> 2, ft = tt & 3;
      f16x8 bf = *(const f16x8*)(WhB +
          ((((size_t)(2 * w + hl) * 8 + ks) * 4 + ft) * 512) + l * 8);
      acc[tt] = __builtin_amdgcn_mfma_f32_16x16x32_f16(af, bf, acc[tt], 0, 0, 0);
    }
  }

  #pragma unroll
  for (int hl = 0; hl < 2; ++hl) {
    int head = 2 * w + hl;
    float a1v[4], a2v[4];
    #pragma unroll
    for (int ft = 0; ft < 4; ++ft) {
      a1v[ft] = ah[head * 128 + ft * 16 + c15] * L2E;
      a2v[ft] = ah[head * 128 + 64 + ft * 16 + c15] * L2E;
    }
    #pragma unroll
    for (int r = 0; r < 4; ++r) {
      float v1 = 0.f, v2 = 0.f;
      #pragma unroll
      for (int ft = 0; ft < 4; ++ft) {
        v1 = fmaf(acc[hl * 4 + ft][r], a1v[ft], v1);
        v2 = fmaf(acc[hl * 4 + ft][r], a2v[ft], v2);
      }
      #pragma unroll
      for (int off = 1; off < 16; off <<= 1) {
        v1 += __shfl_xor(v1, off, 64);
        v2 += __shfl_xor(v2, off, 64);
      }
      if (c15 == 0) {
        s1h[(size_t)(b * NHEADS_ + head) * N_ + n0 + quad * 4 + r] = v1;
        s2h[(size_t)(b * NHEADS_ + head) * N_ + n0 + quad * 4 + r] = v2;
      }
    }
  }

  // transpose: 4 consecutive rows per (f, quad) -> one ds_write_b64
  #pragma unroll
  for (int tt = 0; tt < 8; ++tt) {
    int f = (2 * w + (tt >> 2)) * 64 + (tt & 3) * 16 + c15;
    *(f16x4*)&hT[f * 16 + quad * 4] =
        pack4(acc[tt][0], acc[tt][1], acc[tt][2], acc[tt][3]);
  }
  __syncthreads();

  const int base_oct = (n0 >> 3) & 3;
  #pragma unroll
  for (int q = 0; q < 4; ++q) {
    int s = t + q * 256;
    int c15v = s & 15, oct = (s >> 4) & 1, ft = (s >> 5) & 3, head = s >> 7;
    f16x8 v = *(const f16x8*)&hT[(head * 64 + ft * 16 + c15v) * 16 + oct * 8];
    int lane0 = (base_oct + oct) * 16 + c15v;
    *(f16x8*)(hB1 +
        ((((size_t)(b * NHEADS_ + head) * 64 + (n0 >> 5)) * 4 + ft) * 512) + lane0 * 8) = v;
  }
}

// ---------------------------------------------------------------------------
// GEMM2 (MFMA): block = 16 n-rows x 128 f, 256 thr = 4 waves.
// ---------------------------------------------------------------------------
__global__ __launch_bounds__(256, 4) void k_gemm2(
    const __fp16* __restrict__ g1, const __fp16* __restrict__ WoB,
    const float* __restrict__ ao,
    __fp16* __restrict__ hB2, float* __restrict__ s1o, float* __restrict__ s2o)
{
  constexpr int GP = 520;
  __shared__ __fp16 gs[16 * GP];
  __shared__ __fp16 hT[128 * 16];
  __shared__ float sd1[4][16], sd2[4][16];

  const int t = threadIdx.x;
  const int bid = blockIdx.x;
  const int b = bid >> 7;
  const int n0 = (bid & 127) * 16;

  {
    int r = t >> 4, k0 = (t & 15) * 32;
    const __fp16* src = g1 + ((size_t)(b * N_) + n0 + r) * 512 + k0;
    #pragma unroll
    for (int i = 0; i < 4; ++i)
      *(f16x8*)&gs[r * GP + k0 + i * 8] = *(const f16x8*)(src + i * 8);
  }
  __syncthreads();

  const int w = t >> 6, l = t & 63;
  const int quad = l >> 4, c15 = l & 15;

  f32x4 acc[2];
  acc[0] = (f32x4){0.f, 0.f, 0.f, 0.f};
  acc[1] = (f32x4){0.f, 0.f, 0.f, 0.f};

  for (int ks = 0; ks < 16; ++ks) {
    f16x8 af = *(const f16x8*)&gs[c15 * GP + ks * 32 + quad * 8];
    #pragma unroll
    for (int tt = 0; tt < 2; ++tt) {
      int ft = 2 * w + tt;
      f16x8 bf = *(const f16x8*)(WoB + (((size_t)ks * 8 + ft) * 512) + l * 8);
      acc[tt] = __builtin_amdgcn_mfma_f32_16x16x32_f16(af, bf, acc[tt], 0, 0, 0);
    }
  }

  {
    float a1v[2], a2v[2];
    #pragma unroll
    for (int tt = 0; tt < 2; ++tt) {
      int f = (2 * w + tt) * 16 + c15;
      a1v[tt] = ao[f] * L2E;
      a2v[tt] = ao[128 + f] * L2E;
    }
    #pragma unroll
    for (int r = 0; r < 4; ++r) {
      float v1 = acc[0][r] * a1v[0] + acc[1][r] * a1v[1];
      float v2 = acc[0][r] * a2v[0] + acc[1][r] * a2v[1];
      #pragma unroll
      for (int off = 1; off < 16; off <<= 1) {
        v1 += __shfl_xor(v1, off, 64);
        v2 += __shfl_xor(v2, off, 64);
      }
      if (c15 == 0) { sd1[w][quad * 4 + r] = v1; sd2[w][quad * 4 + r] = v2; }
    }
  }

  #pragma unroll
  for (int tt = 0; tt < 2; ++tt) {
    int f = (2 * w + tt) * 16 + c15;
    *(f16x4*)&hT[f * 16 + quad * 4] =
        pack4(acc[tt][0], acc[tt][1], acc[tt][2], acc[tt][3]);
  }
  __syncthreads();

  if (t < 16)
    s1o[(size_t)b * N_ + n0 + t] = sd1[0][t] + sd1[1][t] + sd1[2][t] + sd1[3][t];
  else if (t < 32) {
    int rr = t - 16;
    s2o[(size_t)b * N_ + n0 + rr] = sd2[0][rr] + sd2[1][rr] + sd2[2][rr] + sd2[3][rr];
  }

  {
    int c15v = t & 15, oct = (t >> 4) & 1, ft = t >> 5;
    f16x8 v = *(const f16x8*)&hT[(ft * 16 + c15v) * 16 + oct * 8];
    int base_oct = (n0 >> 3) & 3;
    int lane0 = (base_oct + oct) * 16 + c15v;
    *(f16x8*)(hB2 +
        (((size_t)(b * 64 + (n0 >> 5)) * 8 + ft) * 512) + lane0 * 8) = v;
  }
}

// ---------------------------------------------------------------------------
// ATT1: layer-1 attention, TJ=128 (4 ksteps/tile, NIT=8 -> half the barriers),
// async global_load_lds dbuf staging, inline s2max from LDS-staged s2 row.
// 72 KB LDS -> 2 blocks/CU -> 4 waves/SIMD -> 128-VGPR budget.
// ---------------------------------------------------------------------------
__global__ __launch_bounds__(512, 4) void k_att1(
    const __fp16* __restrict__ hB, const float* __restrict__ s1,
    const float* __restrict__ s2, const unsigned short* __restrict__ mask2,
    const float* __restrict__ bias, __fp16* __restrict__ g1)
{
  constexpr int NRG = 4, NJQ = 2, JLEN = 1024, TJ = 128, NIT = JLEN / TJ;
  constexpr int TILE = TJ * 64;                // 8192 f16 / slot

  __shared__ __fp16 vbuf[NJQ][2][TILE];        // 64 KB
  __shared__ float s2s[N_];                    // 8 KB
  __shared__ float red[8];

  const int tid = threadIdx.x;
  const int w = tid >> 6, l = tid & 63;
  const int quad = l >> 4, c15 = l & 15;
  const int rowg = w % NRG, jq = w / NRG;
  const int tc = rowg * 64 + l;                // [0,256)

  int idx = blockIdx.x;
  const int ig = idx & 31; idx >>= 5;
  const int head = idx & 7;
  const int b = idx >> 3;
  const int i0w = ig * 64 + rowg * 16;

  const float* s1p = s1 + (size_t)(b * 8 + head) * N_;
  const float* s2p = s2 + (size_t)(b * 8 + head) * N_;
  const char* hBp = (const char*)(hB + (size_t)(b * 8 + head) * (N_ / 32) * 2048);
  const unsigned short* mp = mask2 + ((size_t)(b * 128 + (i0w >> 4)) * 32) * 64 + l;

  const int jbase = jq * JLEN;

  auto stage = [&](int j0, int slot) {         // 4 ksteps contiguous = 16 KB
    const char* srcb = hBp + (size_t)(j0 >> 5) * 4096;
    #pragma unroll
    for (int c = 0; c < 4; ++c) {
      int off = (tc + c * 256) * 16;
      __builtin_amdgcn_global_load_lds(
          (const __attribute__((address_space(1))) unsigned int*)(srcb + off),
          (__attribute__((address_space(3))) unsigned int*)
              ((char*)&vbuf[jq][slot][0] + (off - l * 16)), 16, 0, 0);
    }
  };

  stage(jbase, 0);                             // async, flies over the s2 work
  unsigned int mk0 = mp[(size_t)(jbase >> 6) * 64];
  unsigned int mk1 = mp[(size_t)((jbase >> 6) + 1) * 64];

  // stage s2 row + in-block row max (exact: covers all N)
  float4 sv = *(const float4*)(s2p + tid * 4);
  *(float4*)&s2s[tid * 4] = sv;
  float lm = fmaxf(fmaxf(sv.x, sv.y), fmaxf(sv.z, sv.w));
  #pragma unroll
  for (int off = 1; off < 64; off <<= 1) lm = fmaxf(lm, __shfl_xor(lm, off, 64));
  if (l == 0) red[w] = lm;
  const float s1v = s1p[i0w + c15];
  __syncthreads();                             // drains slot-0 DMA too
  float s2m = red[0];
  #pragma unroll
  for (int q = 1; q < 8; ++q) s2m = fmaxf(s2m, red[q]);

  const float zm = s1v + s2m;
  const float m = fmaxf(zm, SLOPE_ * zm);      // exact unmasked row max
  const float p = s1v - m;
  const float cq = (SLOPE_ - 1.f) * m;

  f16x8 ones;
  #pragma unroll
  for (int i = 0; i < 8; ++i) ones[i] = (__fp16)1.0f;

  f32x4 acc[4], acc5;
  #pragma unroll
  for (int t = 0; t < 4; ++t) acc[t] = (f32x4){0.f, 0.f, 0.f, 0.f};
  acc5 = (f32x4){0.f, 0.f, 0.f, 0.f};

  for (int it = 0; it < NIT; ++it) {
    const int cur = it & 1;
    const int j0 = jbase + it * TJ;
    unsigned int nk0 = 0, nk1 = 0;
    if (it + 1 < NIT) {
      stage(j0 + TJ, cur ^ 1);
      nk0 = mp[(size_t)((j0 + TJ) >> 6) * 64];
      nk1 = mp[(size_t)(((j0 + TJ) >> 6) + 1) * 64];
    }

    #pragma unroll
    for (int h = 0; h < 4; ++h) {              // 4 ksteps of 32 j
      const int jk = j0 + h * 32;
      float s2r[8];
      *(float4*)&s2r[0] = *(const float4*)&s2s[jk + quad * 8];
      *(float4*)&s2r[4] = *(const float4*)&s2s[jk + quad * 8 + 4];
      const unsigned int mk = (h < 2) ? mk0 : mk1;
      const unsigned int mbyte = (mk >> (8 * (h & 1))) & 0xffu;
      float wgt[8];
      #pragma unroll
      for (int k = 0; k < 8; ++k) {
        float t0 = p + s2r[k];
        float t1 = fmaf(SLOPE_, t0, cq);
        float tm = fmaxf(t0, t1);
        float e = __builtin_amdgcn_exp2f(tm);
        int sel = (int)(mbyte << (31 - k)) >> 31;
        union { float f; int i; } u; u.f = e; u.i &= sel;
        wgt[k] = u.f;
      }
      f16x8 a = pack8(wgt);
      acc5 = __builtin_amdgcn_mfma_f32_16x16x32_f16(a, ones, acc5, 0, 0, 0);
      const __fp16* vb = &vbuf[jq][cur][h * 2048];
      #pragma unroll
      for (int t = 0; t < 4; ++t) {
        f16x8 bf = *(const f16x8*)(vb + t * 512 + l * 8);
        acc[t] = __builtin_amdgcn_mfma_f32_16x16x32_f16(a, bf, acc[t], 0, 0, 0);
      }
    }
    mk0 = nk0; mk1 = nk1;
    __syncthreads();
  }

  // combine across the 2 j-chunks (overlay vbuf)
  auto pacc = (float(*)[16][64])(&vbuf[0][0][0]);   // [NRG][16][64]
  auto pls  = (float(*)[16])(&s2s[0]);              // [NRG][16]
  if (jq == 1) {
    #pragma unroll
    for (int t = 0; t < 4; ++t)
      #pragma unroll
      for (int r = 0; r < 4; ++r)
        pacc[rowg][quad * 4 + r][t * 16 + c15] = acc[t][r];
    if (c15 == 0) {
      #pragma unroll
      for (int r = 0; r < 4; ++r) pls[rowg][quad * 4 + r] = acc5[r];
    }
  }
  __syncthreads();
  if (jq == 0) {
    float Lrow[4];
    #pragma unroll
    for (int r = 0; r < 4; ++r)
      Lrow[r] = acc5[r] + pls[rowg][quad * 4 + r];
    #pragma unroll
    for (int t = 0; t < 4; ++t)
      #pragma unroll
      for (int r = 0; r < 4; ++r)
        acc[t][r] += pacc[rowg][quad * 4 + r][t * 16 + c15];
    float lr[4];
    #pragma unroll
    for (int r = 0; r < 4; ++r) lr[r] = 1.f / Lrow[r];
    #pragma unroll
    for (int t = 0; t < 4; ++t) {
      const float bv = bias[head * 64 + t * 16 + c15];
      #pragma unroll
      for (int r = 0; r < 4; ++r) {
        const int i = i0w + quad * 4 + r;
        float v = acc[t][r] * lr[r] + bv;
        v = (v > 0.f) ? v : expm1f(v);          // elu
        g1[(size_t)(b * N_ + i) * 512 + head * 64 + t * 16 + c15] = (__fp16)v;
      }
    }
  }
}

// ---------------------------------------------------------------------------
// ATT2: layer-2 attention, one block covers ALL 128 cols (no fs duplication:
// halves e-work and block count). 8 waves = 2 rowgroups x 4 jchunks; TJ=32
// (one kstep = contiguous 8 KB); async DMA dbuf; inline s2max.
// ---------------------------------------------------------------------------
__global__ __launch_bounds__(512, 2) void k_att2(
    const __fp16* __restrict__ hB, const float* __restrict__ s1,
    const float* __restrict__ s2, const unsigned short* __restrict__ mask2,
    const float* __restrict__ bias, float* __restrict__ out)
{
  constexpr int NRG = 2, NJQ = 4, JLEN = 512, TJ = 32, NIT = JLEN / TJ;
  constexpr int TILE = TJ * 128;               // 4096 f16 / slot

  __shared__ __fp16 vbuf[NJQ][2][TILE];        // 64 KB
  __shared__ float s2s[N_];                    // 8 KB
  __shared__ float red[8];

  const int tid = threadIdx.x;
  const int w = tid >> 6, l = tid & 63;
  const int quad = l >> 4, c15 = l & 15;
  const int rowg = w % NRG, jq = w / NRG;
  const int tc = rowg * 64 + l;                // [0,128)

  int idx = blockIdx.x;
  const int ig = idx & 63;
  const int b = idx >> 6;
  const int i0w = ig * 32 + rowg * 16;

  const float* s1p = s1 + (size_t)b * N_;
  const float* s2p = s2 + (size_t)b * N_;
  const char* hBp = (const char*)(hB + (size_t)b * 64 * 4096);
  const unsigned short* mp = mask2 + ((size_t)(b * 128 + (i0w >> 4)) * 32) * 64 + l;

  const int jbase = jq * JLEN;

  auto stage = [&](int j0, int slot) {         // 1 kstep contiguous = 8 KB
    const char* srcb = hBp + (size_t)(j0 >> 5) * 8192;
    #pragma unroll
    for (int c = 0; c < 4; ++c) {
      int off = (tc + c * 128) * 16;
      __builtin_amdgcn_global_load_lds(
          (const __attribute__((address_space(1))) unsigned int*)(srcb + off),
          (__attribute__((address_space(3))) unsigned int*)
              ((char*)&vbuf[jq][slot][0] + (off - l * 16)), 16, 0, 0);
    }
  };

  stage(jbase, 0);
  unsigned int mk = mp[(size_t)(jbase >> 6) * 64];

  float4 sv = *(const float4*)(s2p + tid * 4);
  *(float4*)&s2s[tid * 4] = sv;
  float lm = fmaxf(fmaxf(sv.x, sv.y), fmaxf(sv.z, sv.w));
  #pragma unroll
  for (int off = 1; off < 64; off <<= 1) lm = fmaxf(lm, __shfl_xor(lm, off, 64));
  if (l == 0) red[w] = lm;
  const float s1v = s1p[i0w + c15];
  __syncthreads();
  float s2m = red[0];
  #pragma unroll
  for (int q = 1; q < 8; ++q) s2m = fmaxf(s2m, red[q]);

  const float zm = s1v + s2m;
  const float m = fmaxf(zm, SLOPE_ * zm);
  const float p = s1v - m;
  const float cq = (SLOPE_ - 1.f) * m;

  f16x8 ones;
  #pragma unroll
  for (int i = 0; i < 8; ++i) ones[i] = (__fp16)1.0f;

  f32x4 acc[8], acc5;
  #pragma unroll
  for (int t = 0; t < 8; ++t) acc[t] = (f32x4){0.f, 0.f, 0.f, 0.f};
  acc5 = (f32x4){0.f, 0.f, 0.f, 0.f};

  for (int it = 0; it < NIT; ++it) {
    const int cur = it & 1;
    const int j0 = jbase + it * TJ;
    unsigned int nk = 0;
    if (it + 1 < NIT) {
      stage(j0 + TJ, cur ^ 1);
      nk = mp[(size_t)((j0 + TJ) >> 6) * 64];
    }

    float s2r[8];
    *(float4*)&s2r[0] = *(const float4*)&s2s[j0 + quad * 8];
    *(float4*)&s2r[4] = *(const float4*)&s2s[j0 + quad * 8 + 4];
    const unsigned int mbyte = (mk >> (8 * ((j0 >> 5) & 1))) & 0xffu;
    float wgt[8];
    #pragma unroll
    for (int k = 0; k < 8; ++k) {
      float t0 = p + s2r[k];
      float t1 = fmaf(SLOPE_, t0, cq);
      float tm = fmaxf(t0, t1);
      float e = __builtin_amdgcn_exp2f(tm);
      int sel = (int)(mbyte << (31 - k)) >> 31;
      union { float f; int i; } u; u.f = e; u.i &= sel;
      wgt[k] = u.f;
    }
    f16x8 a = pack8(wgt);
    acc5 = __builtin_amdgcn_mfma_f32_16x16x32_f16(a, ones, acc5, 0, 0, 0);
    const __fp16* vb = &vbuf[jq][cur][0];
    #pragma unroll
    for (int t = 0; t < 8; ++t) {
      f16x8 bf = *(const f16x8*)(vb + t * 512 + l * 8);
      acc[t] = __builtin_amdgcn_mfma_f32_16x16x32_f16(a, bf, acc[t], 0, 0, 0);
    }
    mk = nk;
    __syncthreads();
  }

  // combine across 4 j-chunks
  auto pacc = (float(*)[NRG][16][128])(&vbuf[0][0][0]);  // [3][2][16][128] 48KB
  auto pls  = (float(*)[NRG][16])(&s2s[0]);              // [3][2][16]
  if (jq > 0) {
    #pragma unroll
    for (int t = 0; t < 8; ++t)
      #pragma unroll
      for (int r = 0; r < 4; ++r)
        pacc[jq - 1][rowg][quad * 4 + r][t * 16 + c15] = acc[t][r];
    if (c15 == 0) {
      #pragma unroll
      for (int r = 0; r < 4; ++r) pls[jq - 1][rowg][quad * 4 + r] = acc5[r];
    }
  }
  __syncthreads();
  if (jq == 0) {
    float Lrow[4];
    #pragma unroll
    for (int r = 0; r < 4; ++r) Lrow[r] = acc5[r];
    #pragma unroll
    for (int q = 0; q < NJQ - 1; ++q) {
      #pragma unroll
      for (int t = 0; t < 8; ++t)
        #pragma unroll
        for (int r = 0; r < 4; ++r)
          acc[t][r] += pacc[q][rowg][quad * 4 + r][t * 16 + c15];
      #pragma unroll
      for (int r = 0; r < 4; ++r) Lrow[r] += pls[q][rowg][quad * 4 + r];
    }
    float lr[4];
    #pragma unroll
    for (int r = 0; r < 4; ++r) lr[r] = 1.f / Lrow[r];
    #pragma unroll
    for (int t = 0; t < 8; ++t) {
      const float bv = bias[t * 16 + c15];
      #pragma unroll
      for (int r = 0; r < 4; ++r) {
        const int i = i0w + quad * 4 + r;
        float v = acc[t][r] * lr[r] + bv;
        out[(size_t)(b * N_ + i) * 128 + t * 16 + c15] = fmaxf(v, 0.f);
      }
    }
  }
}

// ---------------------------------------------------------------------------
extern "C" void kernel_launch(void* const* d_in, const int* in_sizes, int n_in,
                              void* d_out, int out_size, void* d_ws, size_t ws_size,
                              hipStream_t stream) {
  const float* x   = (const float*)d_in[0];
  const int*   adj = (const int*)d_in[1];
  const float* Wh  = (const float*)d_in[2];
  const float* ah  = (const float*)d_in[3];
  const float* bh  = (const float*)d_in[4];
  const float* Wo  = (const float*)d_in[5];
  const float* ao  = (const float*)d_in[6];
  const float* bo  = (const float*)d_in[7];
  float* out = (float*)d_out;

  float* ws   = (float*)d_ws;
  float* s1h  = ws;                                   // B*8*N
  float* s2h  = s1h  + (size_t)B_ * NHEADS_ * N_;
  float* s1o  = s2h  + (size_t)B_ * NHEADS_ * N_;     // B*N
  float* s2o  = s1o  + (size_t)B_ * N_;
  __fp16* g1  = (__fp16*)(s2o + (size_t)B_ * N_);     // B*N*512 f16 (8 MB)
  __fp16* hB1 = g1  + (size_t)B_ * N_ * 512;          // 8 MB
  __fp16* hB2 = hB1 + (size_t)B_ * NHEADS_ * N_ * 64; // 2 MB
  __fp16* WhB = hB2 + (size_t)B_ * N_ * 128;          // 256 KB
  __fp16* WoB = WhB + (size_t)8 * 256 * 64;           // 128 KB
  unsigned short* mask2 = (unsigned short*)(WoB + (size_t)512 * 128); // 2 MB

  k_prep<<<4192, 256, 0, stream>>>(adj, mask2, Wh, WhB, Wo, WoB);
  k_gemm1<<<B_ * (N_ / 16), 256, 0, stream>>>(x, WhB, ah, hB1, s1h, s2h);
  k_att1<<<B_ * NHEADS_ * (N_ / 64), 512, 0, stream>>>(
      hB1, s1h, s2h, mask2, bh, g1);
  k_gemm2<<<B_ * (N_ / 16), 256, 0, stream>>>(g1, WoB, ao, hB2, s1o, s2o);
  k_att2<<<B_ * (N_ / 32), 512, 0, stream>>>(
      hB2, s1o, s2o, mask2, bo, out);
}

// Round 14
// 195.465 us; speedup vs baseline: 1.2565x; 1.0389x over previous
//
#include <hip/hip_runtime.h>

constexpr int B_ = 4;
constexpr int N_ = 2048;
constexpr int NFEAT_ = 256;
constexpr int NHEADS_ = 8;
constexpr float SLOPE_ = 0.1f;
constexpr float L2E = 1.4426950408889634f;   // log2(e)

typedef __attribute__((ext_vector_type(8))) __fp16 f16x8;
typedef __attribute__((ext_vector_type(4))) __fp16 f16x4;
typedef __attribute__((ext_vector_type(2))) __fp16 f16x2;
typedef __attribute__((ext_vector_type(4))) float f32x4;

__device__ __forceinline__ f16x8 pack8(const float* v) {
  union { f16x2 h2[4]; f16x8 h8; } u;
  u.h2[0] = __builtin_amdgcn_cvt_pkrtz(v[0], v[1]);
  u.h2[1] = __builtin_amdgcn_cvt_pkrtz(v[2], v[3]);
  u.h2[2] = __builtin_amdgcn_cvt_pkrtz(v[4], v[5]);
  u.h2[3] = __builtin_amdgcn_cvt_pkrtz(v[6], v[7]);
  return u.h8;
}
__device__ __forceinline__ f16x4 pack4(float a, float b, float c, float d) {
  union { f16x2 h2[2]; f16x4 h4; } u;
  u.h2[0] = __builtin_amdgcn_cvt_pkrtz(a, b);
  u.h2[1] = __builtin_amdgcn_cvt_pkrtz(c, d);
  return u.h4;
}

// ---------------------------------------------------------------------------
// Fused prep: blocks [0,4096) packmask; [4096,4160) prepWh; [4160,4192) prepWo
// ---------------------------------------------------------------------------
__global__ __launch_bounds__(256) void k_prep(
    const int* __restrict__ adj, unsigned short* __restrict__ mask2,
    const float* __restrict__ Wh, __fp16* __restrict__ WhB,
    const float* __restrict__ Wo, __fp16* __restrict__ WoB)
{
  const int bid = blockIdx.x;
  const int l = threadIdx.x & 63;
  if (bid < 4096) {
    const size_t gw = ((size_t)bid * 256 + threadIdx.x) >> 6;
    const int jt = (int)(gw & 31);
    const int ig16 = (int)((gw >> 5) & 127);
    const int b = (int)(gw >> 12);
    const int q = l >> 4, c15 = l & 15;
    const int* base = adj + ((size_t)b * N_ + ig16 * 16) * N_ + jt * 64 + l;
    unsigned int msk = 0;
    #pragma unroll
    for (int r = 0; r < 16; ++r) {
      int a = base[(size_t)r * N_];
      unsigned long long bal = __ballot(a > 0);
      unsigned int v = (unsigned int)((bal >> (q * 8)) & 0xffull)
                     | ((unsigned int)((bal >> (q * 8 + 32)) & 0xffull) << 8);
      if (r == c15) msk = v;
    }
    mask2[gw * 64 + l] = (unsigned short)msk;
  } else if (bid < 4160) {
    int s = (int)(((bid - 4096) * 256 + threadIdx.x) >> 6);   // 0..255
    int h = s >> 5, ks = (s >> 2) & 7, ft = s & 3;
    const float* src = Wh + ((size_t)h * 256 + ks * 32 + (l >> 4) * 8) * 64 + ft * 16 + (l & 15);
    float v[8];
    #pragma unroll
    for (int j = 0; j < 8; ++j) v[j] = src[(size_t)j * 64];
    *(f16x8*)(WhB + (size_t)s * 512 + l * 8) = pack8(v);
  } else {
    int s = (int)(((bid - 4160) * 256 + threadIdx.x) >> 6);   // 0..127
    int ks = s >> 3, ft = s & 7;
    const float* src = Wo + ((size_t)ks * 32 + (l >> 4) * 8) * 128 + ft * 16 + (l & 15);
    float v[8];
    #pragma unroll
    for (int j = 0; j < 8; ++j) v[j] = src[(size_t)j * 128];
    *(f16x8*)(WoB + (size_t)s * 512 + l * 8) = pack8(v);
  }
}

// ---------------------------------------------------------------------------
// GEMM1 (MFMA): block = 16 n-rows x ALL 512 f (8 heads), 256 thr = 4 waves.
// ---------------------------------------------------------------------------
__global__ __launch_bounds__(256, 4) void k_gemm1(
    const float* __restrict__ x, const __fp16* __restrict__ WhB,
    const float* __restrict__ ah,
    __fp16* __restrict__ hB1, float* __restrict__ s1h, float* __restrict__ s2h)
{
  constexpr int XP = 264;
  __shared__ __fp16 xs[16 * XP];
  __shared__ __fp16 hT[512 * 16];

  const int t = threadIdx.x;
  const int bid = blockIdx.x;
  const int b = bid >> 7;
  const int n0 = (bid & 127) * 16;

  {  // stage x -> f16
    int r = t >> 4, k0 = (t & 15) * 16;
    const float* src = x + ((size_t)(b * N_) + n0 + r) * NFEAT_ + k0;
    float v0[8], v1[8];
    *(float4*)&v0[0] = *(const float4*)(src);
    *(float4*)&v0[4] = *(const float4*)(src + 4);
    *(float4*)&v1[0] = *(const float4*)(src + 8);
    *(float4*)&v1[4] = *(const float4*)(src + 12);
    *(f16x8*)&xs[r * XP + k0] = pack8(v0);
    *(f16x8*)&xs[r * XP + k0 + 8] = pack8(v1);
  }
  __syncthreads();

  const int w = t >> 6, l = t & 63;
  const int quad = l >> 4, c15 = l & 15;

  f32x4 acc[8];
  #pragma unroll
  for (int i = 0; i < 8; ++i) acc[i] = (f32x4){0.f, 0.f, 0.f, 0.f};

  for (int ks = 0; ks < 8; ++ks) {
    f16x8 af = *(const f16x8*)&xs[c15 * XP + ks * 32 + quad * 8];
    #pragma unroll
    for (int tt = 0; tt < 8; ++tt) {
      int hl = tt >> 2, ft = tt & 3;
      f16x8 bf = *(const f16x8*)(WhB +
          ((((size_t)(2 * w + hl) * 8 + ks) * 4 + ft) * 512) + l * 8);
      acc[tt] = __builtin_amdgcn_mfma_f32_16x16x32_f16(af, bf, acc[tt], 0, 0, 0);
    }
  }

  #pragma unroll
  for (int hl = 0; hl < 2; ++hl) {
    int head = 2 * w + hl;
    float a1v[4], a2v[4];
    #pragma unroll
    for (int ft = 0; ft < 4; ++ft) {
      a1v[ft] = ah[head * 128 + ft * 16 + c15] * L2E;
      a2v[ft] = ah[head * 128 + 64 + ft * 16 + c15] * L2E;
    }
    #pragma unroll
    for (int r = 0; r < 4; ++r) {
      float v1 = 0.f, v2 = 0.f;
      #pragma unroll
      for (int ft = 0; ft < 4; ++ft) {
        v1 = fmaf(acc[hl * 4 + ft][r], a1v[ft], v1);
        v2 = fmaf(acc[hl * 4 + ft][r], a2v[ft], v2);
      }
      #pragma unroll
      for (int off = 1; off < 16; off <<= 1) {
        v1 += __shfl_xor(v1, off, 64);
        v2 += __shfl_xor(v2, off, 64);
      }
      if (c15 == 0) {
        s1h[(size_t)(b * NHEADS_ + head) * N_ + n0 + quad * 4 + r] = v1;
        s2h[(size_t)(b * NHEADS_ + head) * N_ + n0 + quad * 4 + r] = v2;
      }
    }
  }

  #pragma unroll
  for (int tt = 0; tt < 8; ++tt) {
    int f = (2 * w + (tt >> 2)) * 64 + (tt & 3) * 16 + c15;
    *(f16x4*)&hT[f * 16 + quad * 4] =
        pack4(acc[tt][0], acc[tt][1], acc[tt][2], acc[tt][3]);
  }
  __syncthreads();

  const int base_oct = (n0 >> 3) & 3;
  #pragma unroll
  for (int q = 0; q < 4; ++q) {
    int s = t + q * 256;
    int c15v = s & 15, oct = (s >> 4) & 1, ft = (s >> 5) & 3, head = s >> 7;
    f16x8 v = *(const f16x8*)&hT[(head * 64 + ft * 16 + c15v) * 16 + oct * 8];
    int lane0 = (base_oct + oct) * 16 + c15v;
    *(f16x8*)(hB1 +
        ((((size_t)(b * NHEADS_ + head) * 64 + (n0 >> 5)) * 4 + ft) * 512) + lane0 * 8) = v;
  }
}

// ---------------------------------------------------------------------------
// GEMM2 (MFMA): block = 16 n-rows x 128 f, 256 thr = 4 waves.
// ---------------------------------------------------------------------------
__global__ __launch_bounds__(256, 4) void k_gemm2(
    const __fp16* __restrict__ g1, const __fp16* __restrict__ WoB,
    const float* __restrict__ ao,
    __fp16* __restrict__ hB2, float* __restrict__ s1o, float* __restrict__ s2o)
{
  constexpr int GP = 520;
  __shared__ __fp16 gs[16 * GP];
  __shared__ __fp16 hT[128 * 16];
  __shared__ float sd1[4][16], sd2[4][16];

  const int t = threadIdx.x;
  const int bid = blockIdx.x;
  const int b = bid >> 7;
  const int n0 = (bid & 127) * 16;

  {
    int r = t >> 4, k0 = (t & 15) * 32;
    const __fp16* src = g1 + ((size_t)(b * N_) + n0 + r) * 512 + k0;
    #pragma unroll
    for (int i = 0; i < 4; ++i)
      *(f16x8*)&gs[r * GP + k0 + i * 8] = *(const f16x8*)(src + i * 8);
  }
  __syncthreads();

  const int w = t >> 6, l = t & 63;
  const int quad = l >> 4, c15 = l & 15;

  f32x4 acc[2];
  acc[0] = (f32x4){0.f, 0.f, 0.f, 0.f};
  acc[1] = (f32x4){0.f, 0.f, 0.f, 0.f};

  for (int ks = 0; ks < 16; ++ks) {
    f16x8 af = *(const f16x8*)&gs[c15 * GP + ks * 32 + quad * 8];
    #pragma unroll
    for (int tt = 0; tt < 2; ++tt) {
      int ft = 2 * w + tt;
      f16x8 bf = *(const f16x8*)(WoB + (((size_t)ks * 8 + ft) * 512) + l * 8);
      acc[tt] = __builtin_amdgcn_mfma_f32_16x16x32_f16(af, bf, acc[tt], 0, 0, 0);
    }
  }

  {
    float a1v[2], a2v[2];
    #pragma unroll
    for (int tt = 0; tt < 2; ++tt) {
      int f = (2 * w + tt) * 16 + c15;
      a1v[tt] = ao[f] * L2E;
      a2v[tt] = ao[128 + f] * L2E;
    }
    #pragma unroll
    for (int r = 0; r < 4; ++r) {
      float v1 = acc[0][r] * a1v[0] + acc[1][r] * a1v[1];
      float v2 = acc[0][r] * a2v[0] + acc[1][r] * a2v[1];
      #pragma unroll
      for (int off = 1; off < 16; off <<= 1) {
        v1 += __shfl_xor(v1, off, 64);
        v2 += __shfl_xor(v2, off, 64);
      }
      if (c15 == 0) { sd1[w][quad * 4 + r] = v1; sd2[w][quad * 4 + r] = v2; }
    }
  }

  #pragma unroll
  for (int tt = 0; tt < 2; ++tt) {
    int f = (2 * w + tt) * 16 + c15;
    *(f16x4*)&hT[f * 16 + quad * 4] =
        pack4(acc[tt][0], acc[tt][1], acc[tt][2], acc[tt][3]);
  }
  __syncthreads();

  if (t < 16)
    s1o[(size_t)b * N_ + n0 + t] = sd1[0][t] + sd1[1][t] + sd1[2][t] + sd1[3][t];
  else if (t < 32) {
    int rr = t - 16;
    s2o[(size_t)b * N_ + n0 + rr] = sd2[0][rr] + sd2[1][rr] + sd2[2][rr] + sd2[3][rr];
  }

  {
    int c15v = t & 15, oct = (t >> 4) & 1, ft = t >> 5;
    f16x8 v = *(const f16x8*)&hT[(ft * 16 + c15v) * 16 + oct * 8];
    int base_oct = (n0 >> 3) & 3;
    int lane0 = (base_oct + oct) * 16 + c15v;
    *(f16x8*)(hB2 +
        (((size_t)(b * 64 + (n0 >> 5)) * 8 + ft) * 512) + lane0 * 8) = v;
  }
}

// ---------------------------------------------------------------------------
// ATT1: TJ=64 (R12's measured-best: 40 KB LDS -> 4 blocks/CU, occ ~54%),
// async global_load_lds dbuf, inline s2max from LDS-staged s2 row.
// 8 waves = 4 rowgroups x 2 jchunks of 1024.
// ---------------------------------------------------------------------------
__global__ __launch_bounds__(512, 4) void k_att1(
    const __fp16* __restrict__ hB, const float* __restrict__ s1,
    const float* __restrict__ s2, const unsigned short* __restrict__ mask2,
    const float* __restrict__ bias, __fp16* __restrict__ g1)
{
  constexpr int NRG = 4, NJQ = 2, JLEN = 1024, TJ = 64, NIT = JLEN / TJ;
  constexpr int TILE = TJ * 64;                // 4096 f16 / slot (8 KB)

  __shared__ __fp16 vbuf[NJQ][2][TILE];        // 32 KB
  __shared__ float s2s[N_];                    // 8 KB
  __shared__ float red[8];

  const int tid = threadIdx.x;
  const int w = tid >> 6, l = tid & 63;
  const int quad = l >> 4, c15 = l & 15;
  const int rowg = w % NRG, jq = w / NRG;
  const int tc = rowg * 64 + l;                // [0,256)

  int idx = blockIdx.x;
  const int ig = idx & 31; idx >>= 5;
  const int head = idx & 7;
  const int b = idx >> 3;
  const int i0w = ig * 64 + rowg * 16;

  const float* s1p = s1 + (size_t)(b * 8 + head) * N_;
  const float* s2p = s2 + (size_t)(b * 8 + head) * N_;
  const char* hBp = (const char*)(hB + (size_t)(b * 8 + head) * (N_ / 32) * 2048);
  const unsigned short* mp = mask2 + ((size_t)(b * 128 + (i0w >> 4)) * 32) * 64 + l;

  const int jbase = jq * JLEN;

  auto stage = [&](int j0, int slot) {         // 2 ksteps contiguous = 8 KB
    const char* srcb = hBp + (size_t)(j0 >> 5) * 4096;
    #pragma unroll
    for (int c = 0; c < 2; ++c) {
      int off = (tc + c * 256) * 16;
      __builtin_amdgcn_global_load_lds(
          (const __attribute__((address_space(1))) unsigned int*)(srcb + off),
          (__attribute__((address_space(3))) unsigned int*)
              ((char*)&vbuf[jq][slot][0] + (off - l * 16)), 16, 0, 0);
    }
  };

  stage(jbase, 0);                             // async over the s2 work
  unsigned int mk = mp[(size_t)(jbase >> 6) * 64];

  // stage s2 row + in-block exact row max
  float4 sv = *(const float4*)(s2p + tid * 4);
  *(float4*)&s2s[tid * 4] = sv;
  float lm = fmaxf(fmaxf(sv.x, sv.y), fmaxf(sv.z, sv.w));
  #pragma unroll
  for (int off = 1; off < 64; off <<= 1) lm = fmaxf(lm, __shfl_xor(lm, off, 64));
  if (l == 0) red[w] = lm;
  const float s1v = s1p[i0w + c15];
  __syncthreads();                             // drains slot-0 DMA too
  float s2m = red[0];
  #pragma unroll
  for (int q = 1; q < 8; ++q) s2m = fmaxf(s2m, red[q]);

  const float zm = s1v + s2m;
  const float m = fmaxf(zm, SLOPE_ * zm);      // exact unmasked row max
  const float p = s1v - m;
  const float cq = (SLOPE_ - 1.f) * m;

  f16x8 ones;
  #pragma unroll
  for (int i = 0; i < 8; ++i) ones[i] = (__fp16)1.0f;

  f32x4 acc[4], acc5;
  #pragma unroll
  for (int t = 0; t < 4; ++t) acc[t] = (f32x4){0.f, 0.f, 0.f, 0.f};
  acc5 = (f32x4){0.f, 0.f, 0.f, 0.f};

  for (int it = 0; it < NIT; ++it) {
    const int cur = it & 1;
    const int j0 = jbase + it * TJ;
    unsigned int nk = 0;
    if (it + 1 < NIT) {
      stage(j0 + TJ, cur ^ 1);
      nk = mp[(size_t)((j0 + TJ) >> 6) * 64];
    }

    #pragma unroll
    for (int h = 0; h < 2; ++h) {              // 2 ksteps of 32 j
      const int jk = j0 + h * 32;
      float s2r[8];
      *(float4*)&s2r[0] = *(const float4*)&s2s[jk + quad * 8];
      *(float4*)&s2r[4] = *(const float4*)&s2s[jk + quad * 8 + 4];
      const unsigned int mbyte = (mk >> (8 * h)) & 0xffu;
      float wgt[8];
      #pragma unroll
      for (int k = 0; k < 8; ++k) {
        float t0 = p + s2r[k];
        float t1 = fmaf(SLOPE_, t0, cq);
        float tm = fmaxf(t0, t1);
        float e = __builtin_amdgcn_exp2f(tm);
        int sel = (int)(mbyte << (31 - k)) >> 31;
        union { float f; int i; } u; u.f = e; u.i &= sel;
        wgt[k] = u.f;
      }
      f16x8 a = pack8(wgt);
      acc5 = __builtin_amdgcn_mfma_f32_16x16x32_f16(a, ones, acc5, 0, 0, 0);
      const __fp16* vb = &vbuf[jq][cur][h * 2048];
      #pragma unroll
      for (int t = 0; t < 4; ++t) {
        f16x8 bf = *(const f16x8*)(vb + t * 512 + l * 8);
        acc[t] = __builtin_amdgcn_mfma_f32_16x16x32_f16(a, bf, acc[t], 0, 0, 0);
      }
    }
    mk = nk;
    __syncthreads();
  }

  // combine across the 2 j-chunks (overlay vbuf/s2s)
  auto pacc = (float(*)[16][64])(&vbuf[0][0][0]);   // [NRG][16][64] = 16 KB
  auto pls  = (float(*)[16])(&s2s[0]);              // [NRG][16]
  if (jq == 1) {
    #pragma unroll
    for (int t = 0; t < 4; ++t)
      #pragma unroll
      for (int r = 0; r < 4; ++r)
        pacc[rowg][quad * 4 + r][t * 16 + c15] = acc[t][r];
    if (c15 == 0) {
      #pragma unroll
      for (int r = 0; r < 4; ++r) pls[rowg][quad * 4 + r] = acc5[r];
    }
  }
  __syncthreads();
  if (jq == 0) {
    float Lrow[4];
    #pragma unroll
    for (int r = 0; r < 4; ++r)
      Lrow[r] = acc5[r] + pls[rowg][quad * 4 + r];
    #pragma unroll
    for (int t = 0; t < 4; ++t)
      #pragma unroll
      for (int r = 0; r < 4; ++r)
        acc[t][r] += pacc[rowg][quad * 4 + r][t * 16 + c15];
    float lr[4];
    #pragma unroll
    for (int r = 0; r < 4; ++r) lr[r] = 1.f / Lrow[r];
    #pragma unroll
    for (int t = 0; t < 4; ++t) {
      const float bv = bias[head * 64 + t * 16 + c15];
      #pragma unroll
      for (int r = 0; r < 4; ++r) {
        const int i = i0w + quad * 4 + r;
        float v = acc[t][r] * lr[r] + bv;
        v = (v > 0.f) ? v : expm1f(v);          // elu
        g1[(size_t)(b * N_ + i) * 512 + head * 64 + t * 16 + c15] = (__fp16)v;
      }
    }
  }
}

// ---------------------------------------------------------------------------
// ATT2: fs column-split restored for parallelism — R13's full-width variant
// ran only 256 blocks = 1 block/CU (latency-bound, no barrier overlap).
// 512 blocks of 32 rows x 64 cols; 8 waves = 2 rowgroups x 4 jchunks of 512;
// TJ=32 (fs half-kstep = 4 KB contiguous); 40 KB LDS -> 4 blocks/CU.
// ---------------------------------------------------------------------------
__global__ __launch_bounds__(512, 4) void k_att2(
    const __fp16* __restrict__ hB, const float* __restrict__ s1,
    const float* __restrict__ s2, const unsigned short* __restrict__ mask2,
    const float* __restrict__ bias, float* __restrict__ out)
{
  constexpr int NRG = 2, NJQ = 4, JLEN = 512, TJ = 32, NIT = JLEN / TJ;
  constexpr int TILE = TJ * 64;                // 2048 f16 / slot (4 KB)

  __shared__ __fp16 vbuf[NJQ][2][TILE];        // 32 KB
  __shared__ float s2s[N_];                    // 8 KB
  __shared__ float red[8];

  const int tid = threadIdx.x;
  const int w = tid >> 6, l = tid & 63;
  const int quad = l >> 4, c15 = l & 15;
  const int rowg = w % NRG, jq = w / NRG;
  const int tc = rowg * 64 + l;                // [0,128)

  int idx = blockIdx.x;
  const int ig = idx & 63; idx >>= 6;
  const int fs = idx & 1;
  const int b = idx >> 1;
  const int i0w = ig * 32 + rowg * 16;

  const float* s1p = s1 + (size_t)b * N_;
  const float* s2p = s2 + (size_t)b * N_;
  const char* hBp = (const char*)(hB + (size_t)b * 64 * 4096 + fs * 2048);
  const unsigned short* mp = mask2 + ((size_t)(b * 128 + (i0w >> 4)) * 32) * 64 + l;

  const int jbase = jq * JLEN;

  auto stage = [&](int j0, int slot) {         // fs half-kstep = 4 KB contig
    const char* srcb = hBp + (size_t)(j0 >> 5) * 8192;
    #pragma unroll
    for (int c = 0; c < 2; ++c) {
      int off = (tc + c * 128) * 16;
      __builtin_amdgcn_global_load_lds(
          (const __attribute__((address_space(1))) unsigned int*)(srcb + off),
          (__attribute__((address_space(3))) unsigned int*)
              ((char*)&vbuf[jq][slot][0] + (off - l * 16)), 16, 0, 0);
    }
  };

  stage(jbase, 0);
  unsigned int mk = mp[(size_t)(jbase >> 6) * 64];

  float4 sv = *(const float4*)(s2p + tid * 4);
  *(float4*)&s2s[tid * 4] = sv;
  float lm = fmaxf(fmaxf(sv.x, sv.y), fmaxf(sv.z, sv.w));
  #pragma unroll
  for (int off = 1; off < 64; off <<= 1) lm = fmaxf(lm, __shfl_xor(lm, off, 64));
  if (l == 0) red[w] = lm;
  const float s1v = s1p[i0w + c15];
  __syncthreads();
  float s2m = red[0];
  #pragma unroll
  for (int q = 1; q < 8; ++q) s2m = fmaxf(s2m, red[q]);

  const float zm = s1v + s2m;
  const float m = fmaxf(zm, SLOPE_ * zm);
  const float p = s1v - m;
  const float cq = (SLOPE_ - 1.f) * m;

  f16x8 ones;
  #pragma unroll
  for (int i = 0; i < 8; ++i) ones[i] = (__fp16)1.0f;

  f32x4 acc[4], acc5;
  #pragma unroll
  for (int t = 0; t < 4; ++t) acc[t] = (f32x4){0.f, 0.f, 0.f, 0.f};
  acc5 = (f32x4){0.f, 0.f, 0.f, 0.f};

  for (int it = 0; it < NIT; ++it) {
    const int cur = it & 1;
    const int j0 = jbase + it * TJ;
    unsigned int nk = 0;
    if (it + 1 < NIT) {
      stage(j0 + TJ, cur ^ 1);
      nk = mp[(size_t)((j0 + TJ) >> 6) * 64];
    }

    float s2r[8];
    *(float4*)&s2r[0] = *(const float4*)&s2s[j0 + quad * 8];
    *(float4*)&s2r[4] = *(const float4*)&s2s[j0 + quad * 8 + 4];
    const unsigned int mbyte = (mk >> (8 * ((j0 >> 5) & 1))) & 0xffu;
    float wgt[8];
    #pragma unroll
    for (int k = 0; k < 8; ++k) {
      float t0 = p + s2r[k];
      float t1 = fmaf(SLOPE_, t0, cq);
      float tm = fmaxf(t0, t1);
      float e = __builtin_amdgcn_exp2f(tm);
      int sel = (int)(mbyte << (31 - k)) >> 31;
      union { float f; int i; } u; u.f = e; u.i &= sel;
      wgt[k] = u.f;
    }
    f16x8 a = pack8(wgt);
    acc5 = __builtin_amdgcn_mfma_f32_16x16x32_f16(a, ones, acc5, 0, 0, 0);
    const __fp16* vb = &vbuf[jq][cur][0];
    #pragma unroll
    for (int t = 0; t < 4; ++t) {
      f16x8 bf = *(const f16x8*)(vb + t * 512 + l * 8);
      acc[t] = __builtin_amdgcn_mfma_f32_16x16x32_f16(a, bf, acc[t], 0, 0, 0);
    }
    mk = nk;
    __syncthreads();
  }

  // combine across 4 j-chunks (overlay: pacc 24 KB in vbuf, pls in s2s)
  auto pacc = (float(*)[NRG][16][64])(&vbuf[0][0][0]);
  auto pls  = (float(*)[NRG][16])(&s2s[0]);
  if (jq > 0) {
    #pragma unroll
    for (int t = 0; t < 4; ++t)
      #pragma unroll
      for (int r = 0; r < 4; ++r)
        pacc[jq - 1][rowg][quad * 4 + r][t * 16 + c15] = acc[t][r];
    if (c15 == 0) {
      #pragma unroll
      for (int r = 0; r < 4; ++r) pls[jq - 1][rowg][quad * 4 + r] = acc5[r];
    }
  }
  __syncthreads();
  if (jq == 0) {
    float Lrow[4];
    #pragma unroll
    for (int r = 0; r < 4; ++r) Lrow[r] = acc5[r];
    #pragma unroll
    for (int q = 0; q < NJQ - 1; ++q) {
      #pragma unroll
      for (int t = 0; t < 4; ++t)
        #pragma unroll
        for (int r = 0; r < 4; ++r)
          acc[t][r] += pacc[q][rowg][quad * 4 + r][t * 16 + c15];
      #pragma unroll
      for (int r = 0; r < 4; ++r) Lrow[r] += pls[q][rowg][quad * 4 + r];
    }
    float lr[4];
    #pragma unroll
    for (int r = 0; r < 4; ++r) lr[r] = 1.f / Lrow[r];
    #pragma unroll
    for (int t = 0; t < 4; ++t) {
      const float bv = bias[fs * 64 + t * 16 + c15];
      #pragma unroll
      for (int r = 0; r < 4; ++r) {
        const int i = i0w + quad * 4 + r;
        float v = acc[t][r] * lr[r] + bv;
        out[(size_t)(b * N_ + i) * 128 + fs * 64 + t * 16 + c15] = fmaxf(v, 0.f);
      }
    }
  }
}

// ---------------------------------------------------------------------------
extern "C" void kernel_launch(void* const* d_in, const int* in_sizes, int n_in,
                              void* d_out, int out_size, void* d_ws, size_t ws_size,
                              hipStream_t stream) {
  const float* x   = (const float*)d_in[0];
  const int*   adj = (const int*)d_in[1];
  const float* Wh  = (const float*)d_in[2];
  const float* ah  = (const float*)d_in[3];
  const float* bh  = (const float*)d_in[4];
  const float* Wo  = (const float*)d_in[5];
  const float* ao  = (const float*)d_in[6];
  const float* bo  = (const float*)d_in[7];
  float* out = (float*)d_out;

  float* ws   = (float*)d_ws;
  float* s1h  = ws;                                   // B*8*N
  float* s2h  = s1h  + (size_t)B_ * NHEADS_ * N_;
  float* s1o  = s2h  + (size_t)B_ * NHEADS_ * N_;     // B*N
  float* s2o  = s1o  + (size_t)B_ * N_;
  __fp16* g1  = (__fp16*)(s2o + (size_t)B_ * N_);     // B*N*512 f16 (8 MB)
  __fp16* hB1 = g1  + (size_t)B_ * N_ * 512;          // 8 MB
  __fp16* hB2 = hB1 + (size_t)B_ * NHEADS_ * N_ * 64; // 2 MB
  __fp16* WhB = hB2 + (size_t)B_ * N_ * 128;          // 256 KB
  __fp16* WoB = WhB + (size_t)8 * 256 * 64;           // 128 KB
  unsigned short* mask2 = (unsigned short*)(WoB + (size_t)512 * 128); // 2 MB

  k_prep<<<4192, 256, 0, stream>>>(adj, mask2, Wh, WhB, Wo, WoB);
  k_gemm1<<<B_ * (N_ / 16), 256, 0, stream>>>(x, WhB, ah, hB1, s1h, s2h);
  k_att1<<<B_ * NHEADS_ * (N_ / 64), 512, 0, stream>>>(
      hB1, s1h, s2h, mask2, bh, g1);
  k_gemm2<<<B_ * (N_ / 16), 256, 0, stream>>>(g1, WoB, ao, hB2, s1o, s2o);
  k_att2<<<B_ * 2 * (N_ / 32), 512, 0, stream>>>(
      hB2, s1o, s2o, mask2, bo, out);
}